// Round 15
// baseline (436.424 us; speedup 1.0000x reference)
//
#include <hip/hip_runtime.h>
#include <math.h>

#define NN   10000   // nodes
#define NE   160000  // edges
#define CCH  64      // in/out channels
#define TIN  12      // input time steps
#define HCH  64      // hidden channels
#define TSP  10      // T - 2
#define FF   640     // H * TSP
#define TOUT 8       // TSP - 2
#define NR   (NN * TSP)    // 100000 rows for tcn1 / GCN / greto
#define NR2  (NN * TOUT)   // 80000 rows for tcn2

// GCN feature ordering: f' = t*64 + h (channel-contiguous rows)

typedef _Float16 f16;
typedef _Float16 f16x2 __attribute__((ext_vector_type(2)));
typedef _Float16 f16x8 __attribute__((ext_vector_type(8)));
typedef float f32x4 __attribute__((ext_vector_type(4)));

// async global->LDS, 16B per lane, wave-uniform LDS base + lane*16
#define GLD_LDS(gsrc, ldst) __builtin_amdgcn_global_load_lds( \
    (const __attribute__((address_space(1))) void*)(gsrc),    \
    (__attribute__((address_space(3))) void*)(ldst), 16, 0, 0)

// ---------------- x transpose: xT[n][t][c] = (f16)x[n][c][t] ----------------
__global__ __launch_bounds__(256) void k_xT(const float* __restrict__ x, f16* __restrict__ xT)
{
    __shared__ float xs[4][CCH * TIN];
    int node0 = blockIdx.x * 4;
    for (int i = threadIdx.x; i < 4 * CCH * TIN; i += 256) {
        int nn = i / (CCH * TIN), off = i % (CCH * TIN);
        int g = node0 + nn;
        xs[nn][off] = (g < NN) ? x[(size_t)g * CCH * TIN + off] : 0.f;
    }
    __syncthreads();
    for (int i = threadIdx.x; i < 4 * CCH * TIN; i += 256) {
        int nn = i / (CCH * TIN), off = i % (CCH * TIN);
        int t = off >> 6, c = off & 63;
        int g = node0 + nn;
        if (g < NN) xT[(size_t)g * (CCH * TIN) + off] = (f16)xs[nn][c * TIN + t];
    }
}

// ---------------- conv weights -> Bw[o][k*64+ci] f16 ------------------------
__global__ void k_wconv(const float* __restrict__ w1, const float* __restrict__ w2,
                        f16* __restrict__ dst)
{
    int tid = blockIdx.x * 256 + threadIdx.x;
    if (tid >= 128 * 192) return;
    int o = tid / 192, j = tid % 192;
    int k = j >> 6, ci = j & 63;
    const float* src = (o < 64) ? w1 : w2;
    dst[tid] = (f16)src[((o & 63) * 64 + ci) * 3 + k];
}

// ---------------- TCN1 as direct GEMM, B staged in LDS ----------------------
__global__ __launch_bounds__(256) void k_tcn1g(const f16* __restrict__ A,   // xT [NN][768]
                                               const f16* __restrict__ Bw,
                                               const float* __restrict__ b1,
                                               const float* __restrict__ b2,
                                               f16* __restrict__ out)       // [NR][64] = f' order
{
    __shared__ f16 Bs[128][200];   // padded: row stride 100 dwords -> 2-way alias only
    int tid = threadIdx.x;
#pragma unroll
    for (int i = 0; i < 12; ++i) {
        int c = tid + i * 256;             // 3072 f16x8 chunks
        int row = c / 24, seg = (c % 24) * 8;
        *(f16x8*)&Bs[row][seg] = *(const f16x8*)&Bw[row * 192 + seg];
    }
    __syncthreads();

    int w = tid >> 6, l = tid & 63;
    int row0 = blockIdx.x * 128 + w * 32;
    int lrow = l & 15, lk = (l >> 4) * 8;

    size_t abase[2];
#pragma unroll
    for (int m = 0; m < 2; ++m) {
        int rr = row0 + m * 16 + lrow;
        int rc = (rr < NR) ? rr : NR - 1;
        int n = rc / 10, t = rc - n * 10;
        abase[m] = (size_t)n * 768 + t * 64 + lk;
    }
    f32x4 acc[2][8];
#pragma unroll
    for (int m = 0; m < 2; ++m)
#pragma unroll
        for (int n = 0; n < 8; ++n)
            acc[m][n] = (f32x4){0.f, 0.f, 0.f, 0.f};

#pragma unroll
    for (int ks = 0; ks < 6; ++ks) {
        f16x8 af[2], bf[8];
#pragma unroll
        for (int m = 0; m < 2; ++m)
            af[m] = *(const f16x8*)&A[abase[m] + ks * 32];
#pragma unroll
        for (int n = 0; n < 8; ++n)
            bf[n] = *(const f16x8*)&Bs[n * 16 + lrow][ks * 32 + lk];
#pragma unroll
        for (int m = 0; m < 2; ++m)
#pragma unroll
            for (int n = 0; n < 8; ++n)
                acc[m][n] = __builtin_amdgcn_mfma_f32_16x16x32_f16(af[m], bf[n], acc[m][n], 0, 0, 0);
    }
    int og = (l >> 4) * 4;
#pragma unroll
    for (int m = 0; m < 2; ++m) {
#pragma unroll
        for (int n = 0; n < 4; ++n) {
            int h = n * 16 + lrow;
            float bb1 = b1[h], bb2 = b2[h];
#pragma unroll
            for (int rr = 0; rr < 4; ++rr) {
                int R = row0 + m * 16 + og + rr;
                if (R < NR) {
                    float g1 = acc[m][n][rr] + bb1;
                    float g2 = acc[m][n + 4][rr] + bb2;
                    float e = __expf(2.f * g1);
                    float th = 1.f - 2.f / (e + 1.f);
                    float sg = 1.f / (1.f + __expf(-g2));
                    out[(size_t)R * 64 + h] = (f16)(th * sg);
                }
            }
        }
    }
}

// TCN2: A = Gbuf [NN][640] f16, rows r=n*8+t, slice at n*640+t*64; f32 out [N,64,8]
__global__ __launch_bounds__(256) void k_tcn2g(const f16* __restrict__ A,
                                               const f16* __restrict__ Bw,
                                               const float* __restrict__ b1,
                                               const float* __restrict__ b2,
                                               float* __restrict__ out)
{
    __shared__ f16 Bs[128][200];
    int tid = threadIdx.x;
#pragma unroll
    for (int i = 0; i < 12; ++i) {
        int c = tid + i * 256;
        int row = c / 24, seg = (c % 24) * 8;
        *(f16x8*)&Bs[row][seg] = *(const f16x8*)&Bw[row * 192 + seg];
    }
    __syncthreads();

    int w = tid >> 6, l = tid & 63;
    int row0 = blockIdx.x * 128 + w * 32;
    int lrow = l & 15, lk = (l >> 4) * 8;

    size_t abase[2];
#pragma unroll
    for (int m = 0; m < 2; ++m) {
        int rr = row0 + m * 16 + lrow;
        int rc = (rr < NR2) ? rr : NR2 - 1;
        int n = rc >> 3, t = rc & 7;
        abase[m] = (size_t)n * FF + t * 64 + lk;
    }
    f32x4 acc[2][8];
#pragma unroll
    for (int m = 0; m < 2; ++m)
#pragma unroll
        for (int n = 0; n < 8; ++n)
            acc[m][n] = (f32x4){0.f, 0.f, 0.f, 0.f};

#pragma unroll
    for (int ks = 0; ks < 6; ++ks) {
        f16x8 af[2], bf[8];
#pragma unroll
        for (int m = 0; m < 2; ++m)
            af[m] = *(const f16x8*)&A[abase[m] + ks * 32];
#pragma unroll
        for (int n = 0; n < 8; ++n)
            bf[n] = *(const f16x8*)&Bs[n * 16 + lrow][ks * 32 + lk];
#pragma unroll
        for (int m = 0; m < 2; ++m)
#pragma unroll
            for (int n = 0; n < 8; ++n)
                acc[m][n] = __builtin_amdgcn_mfma_f32_16x16x32_f16(af[m], bf[n], acc[m][n], 0, 0, 0);
    }
    int og = (l >> 4) * 4;
#pragma unroll
    for (int m = 0; m < 2; ++m) {
#pragma unroll
        for (int n = 0; n < 4; ++n) {
            int c = n * 16 + lrow;
            float bb1 = b1[c], bb2 = b2[c];
#pragma unroll
            for (int rr = 0; rr < 4; ++rr) {
                int R = row0 + m * 16 + og + rr;
                if (R < NR2) {
                    float g1 = acc[m][n][rr] + bb1;
                    float g2 = acc[m][n + 4][rr] + bb2;
                    float e = __expf(2.f * g1);
                    float th = 1.f - 2.f / (e + 1.f);
                    float sg = 1.f / (1.f + __expf(-g2));
                    int n2 = R >> 3, t2 = R & 7;
                    out[(size_t)n2 * (CCH * TOUT) + c * TOUT + t2] = th * sg;
                }
            }
        }
    }
}

// ---------------- psi MLP ---------------------------------------------------
__global__ void k_psi(const float* __restrict__ ND, const float* __restrict__ W1,
                      const float* __restrict__ b1, const float* __restrict__ W2,
                      const float* __restrict__ b2, float* __restrict__ psi)
{
    int n = blockIdx.x * blockDim.x + threadIdx.x;
    if (n >= NN) return;
    float d0 = ND[n * 3], d1 = ND[n * 3 + 1], d2 = ND[n * 3 + 2];
    float o0 = b2[0], o1 = b2[1], o2 = b2[2];
    for (int j = 0; j < 64; ++j) {
        float hv = d0 * W1[j] + d1 * W1[64 + j] + d2 * W1[128 + j] + b1[j];
        hv = fmaxf(hv, 0.f);
        o0 += hv * W2[j * 3 + 0];
        o1 += hv * W2[j * 3 + 1];
        o2 += hv * W2[j * 3 + 2];
    }
    psi[n * 3 + 0] = o0; psi[n * 3 + 1] = o1; psi[n * 3 + 2] = o2;
}

// ---------------- degree / counts -------------------------------------------
__global__ void k_deg(const int* __restrict__ ei, const float* __restrict__ ea,
                      int* __restrict__ cnt, float* __restrict__ degp, float* __restrict__ degn)
{
    int e = blockIdx.x * blockDim.x + threadIdx.x;
    if (e >= NE) return;
    int d = ei[NE + e];
    atomicAdd(&cnt[d], 1);
    atomicAdd(&degp[d], ea[e * 2 + 0] + 1.f);
    atomicAdd(&degn[d], ea[e * 2 + 1] + 1.f);
}

__global__ void k_dis(const float* __restrict__ degp, const float* __restrict__ degn,
                      float* __restrict__ disp, float* __restrict__ disn)
{
    int n = blockIdx.x * blockDim.x + threadIdx.x;
    if (n >= NN) return;
    disp[n] = 1.f / sqrtf(degp[n] + 1.f);
    disn[n] = 1.f / sqrtf(degn[n] + 1.f);
}

// ---------------- exclusive scan --------------------------------------------
__global__ __launch_bounds__(1024) void k_scan(const int* __restrict__ cnt, int* __restrict__ rowptr)
{
    __shared__ int buf[1024];
    __shared__ int carry;
    if (threadIdx.x == 0) carry = 0;
    __syncthreads();
    for (int base = 0; base < NN; base += 1024) {
        int i = base + threadIdx.x;
        int v = (i < NN) ? cnt[i] : 0;
        buf[threadIdx.x] = v;
        __syncthreads();
        for (int off = 1; off < 1024; off <<= 1) {
            int t = (threadIdx.x >= (unsigned)off) ? buf[threadIdx.x - off] : 0;
            __syncthreads();
            buf[threadIdx.x] += t;
            __syncthreads();
        }
        if (i < NN) rowptr[i] = carry + buf[threadIdx.x] - v;
        __syncthreads();
        if (threadIdx.x == 0) carry += buf[1023];
        __syncthreads();
    }
    if (threadIdx.x == 0) rowptr[NN] = carry;
}

// ---------------- CSR fill ---------------------------------------------------
__global__ void k_fill(const int* __restrict__ ei, const float* __restrict__ ea,
                       const int* __restrict__ rowptr, int* __restrict__ cursor,
                       const float* __restrict__ disp, const float* __restrict__ disn,
                       int* __restrict__ colsrc, float* __restrict__ normp, float* __restrict__ normn)
{
    int e = blockIdx.x * blockDim.x + threadIdx.x;
    if (e >= NE) return;
    int s = ei[e], d = ei[NE + e];
    int slot = atomicAdd(&cursor[d], 1);
    int idx = rowptr[d] + slot;
    colsrc[idx] = s;
    normp[idx] = disp[s] * (ea[e * 2 + 0] + 1.f) * disp[d];
    normn[idx] = disn[s] * (ea[e * 2 + 1] + 1.f) * disn[d];
}

// ---------------- W transpose+cast: Wt0[n][k] = (f16)W[k][n] ----------------
__global__ __launch_bounds__(256) void k_wsplit(const float* __restrict__ W, f16* __restrict__ Wt)
{
    __shared__ float t[32][33];
    int bx = blockIdx.x * 32;
    int by = blockIdx.y * 32;
    int tx = threadIdx.x & 31, ty = threadIdx.x >> 5;
#pragma unroll
    for (int j = 0; j < 4; ++j)
        t[ty + j * 8][tx] = W[(size_t)(bx + ty + j * 8) * 640 + by + tx];
    __syncthreads();
#pragma unroll
    for (int j = 0; j < 4; ++j)
        Wt[(size_t)(by + ty + j * 8) * 640 + bx + tx] = (f16)t[tx][ty + j * 8];
}

// ---------------- permute rows+cols to f' order -----------------------------
__global__ __launch_bounds__(640) void k_perm(const f16* __restrict__ Wt0, f16* __restrict__ Wt)
{
    __shared__ f16 row[FF];
    int np = blockIdx.x;
    int n = (np & 63) * 10 + (np >> 6);
    int tid = threadIdx.x;
    row[tid] = Wt0[(size_t)n * FF + tid];
    __syncthreads();
    int k = (tid & 63) * 10 + (tid >> 6);
    Wt[(size_t)np * FF + tid] = row[k];
}

// ---------------- gW transpose: gWt[d][c] = (f16)gW[c][d] -------------------
__global__ void k_gwt(const float* __restrict__ gW, f16* __restrict__ gWt)
{
    int tid = blockIdx.x * 256 + threadIdx.x;
    if (tid >= 128 * 64) return;
    int c = tid >> 6, d = tid & 63;
    gWt[d * 128 + c] = (f16)gW[tid];
}

// ---------------- f16 MFMA GEMM with global_load_lds staging ----------------
// C[M,640] = A[M,640] @ Bt^T (f16 out); tile 128x64, BK=32, 4 waves
__global__ __launch_bounds__(256) void k_gemm16(const f16* __restrict__ A,
                                                const f16* __restrict__ Bt,
                                                f16* __restrict__ C, int M)
{
    __shared__ f16 As[128 * 32];   // linear [row][32]
    __shared__ f16 Bs[64 * 32];
    int tid = threadIdx.x;
    int row0 = blockIdx.x * 128;
    int col0 = blockIdx.y * 64;
    int w = tid >> 6, l = tid & 63;
    int wr = (w >> 1) * 64;
    int wc = (w & 1) * 32;
    int lrow = l & 15;
    int lk = (l >> 4) * 8;

    int arow = w * 32 + (l >> 2);
    int brow = w * 16 + (l >> 2);
    int seg  = (l & 3) * 8;

    f32x4 acc[4][2];
#pragma unroll
    for (int m = 0; m < 4; ++m)
#pragma unroll
        for (int n = 0; n < 2; ++n)
            acc[m][n] = (f32x4){0.f, 0.f, 0.f, 0.f};

    for (int k0 = 0; k0 < FF; k0 += 32) {
        __syncthreads();
        GLD_LDS(&A[(size_t)(row0 + arow) * FF + k0 + seg],       &As[w * 1024]);
        GLD_LDS(&A[(size_t)(row0 + arow + 16) * FF + k0 + seg],  &As[w * 1024 + 512]);
        GLD_LDS(&Bt[(size_t)(col0 + brow) * FF + k0 + seg],      &Bs[w * 512]);
        __syncthreads();
        f16x8 af[4], bf[2];
#pragma unroll
        for (int m = 0; m < 4; ++m)
            af[m] = *(const f16x8*)&As[(wr + m * 16 + lrow) * 32 + lk];
#pragma unroll
        for (int n = 0; n < 2; ++n)
            bf[n] = *(const f16x8*)&Bs[(wc + n * 16 + lrow) * 32 + lk];
#pragma unroll
        for (int m = 0; m < 4; ++m)
#pragma unroll
            for (int n = 0; n < 2; ++n)
                acc[m][n] = __builtin_amdgcn_mfma_f32_16x16x32_f16(af[m], bf[n], acc[m][n], 0, 0, 0);
    }
    int orow = (l >> 4) * 4;
#pragma unroll
    for (int m = 0; m < 4; ++m) {
#pragma unroll
        for (int r = 0; r < 4; ++r) {
            int rr = row0 + wr + m * 16 + orow + r;
            if (rr < M) {
#pragma unroll
                for (int n = 0; n < 2; ++n)
                    C[(size_t)rr * FF + col0 + wc + n * 16 + lrow] = (f16)acc[m][n][r];
            }
        }
    }
}

// ---------------- GCN aggregate: stripe-per-XCD decomposition ---------------
// grid = NN*8 blocks of 64 threads; block b: node = b>>3, stripe = b&7.
// Stripe covers 80 f16 cols [stripe*80, stripe*80+80); lanes 0..39 do f16x2.
// stripe == b%8 -> all blocks of a stripe land on one XCD (round-robin
// dispatch), so per-XCD L2 working set is ~2.6 MB (< 4 MiB) instead of 12.8 MB.
__global__ __launch_bounds__(64) void k_agg(const f16* __restrict__ hsrc,
                      const int* __restrict__ rowptr, const int* __restrict__ colsrc,
                      const float* __restrict__ enorm, const float* __restrict__ dis,
                      const float* __restrict__ bias, f16* __restrict__ hout)
{
    __shared__ int   s_idx[128];
    __shared__ float s_w[128];
    int d = blockIdx.x >> 3;
    int stripe = blockIdx.x & 7;
    int lane = threadIdx.x;
    int c0 = stripe * 80 + lane * 2;     // lanes 0..39 active in gather
    bool act = lane < 40;
    float selfw = dis[d] * dis[d];
    float v0 = 0.f, v1 = 0.f;
    if (act) {
        f16x2 self = *(const f16x2*)&hsrc[(size_t)d * FF + c0];
        v0 = selfw * (float)self[0];
        v1 = selfw * (float)self[1];
    }
    int beg = rowptr[d], end = rowptr[d + 1];
    for (int base = beg; base < end; base += 128) {
        int cnt = (end - base < 128) ? (end - base) : 128;
        __syncthreads();
        for (int j = lane; j < cnt; j += 64) {
            s_idx[j] = colsrc[base + j];
            s_w[j]   = enorm[base + j];
        }
        __syncthreads();
        if (act) {
            for (int i = 0; i < cnt; ++i) {
                f16x2 p = *(const f16x2*)&hsrc[(size_t)s_idx[i] * FF + c0];
                float w = s_w[i];
                v0 += w * (float)p[0];
                v1 += w * (float)p[1];
            }
        }
    }
    if (act) {
        int c1 = c0 + 1;
        v0 += bias[(c0 & 63) * 10 + (c0 >> 6)];
        v1 += bias[(c1 & 63) * 10 + (c1 >> 6)];
        f16x2 o;
        o[0] = (f16)fmaxf(v0, 0.f);
        o[1] = (f16)fmaxf(v1, 0.f);
        *(f16x2*)&hout[(size_t)d * FF + c0] = o;
    }
}

// ---------------- GReTo mix as MFMA GEMM (f16 out) --------------------------
__global__ __launch_bounds__(256) void k_greto2(const f16* __restrict__ h1,
                        const f16* __restrict__ h2, const f16* __restrict__ h3,
                        const f16* __restrict__ hneg, const float* __restrict__ psi,
                        const f16* __restrict__ gWt, const float* __restrict__ gb,
                        f16* __restrict__ out)
{
    __shared__ f16 As[128][132];
    __shared__ f16 Bs[64][132];
    int tid = threadIdx.x;
    int row0 = blockIdx.x * 128;

    for (int cb = tid; cb < 1024; cb += 256) {
        int d = cb >> 4, seg = (cb & 15) * 8;
        *(f16x8*)&Bs[d][seg] = *(const f16x8*)&gWt[d * 128 + seg];
    }
    int lr = tid >> 1, side = tid & 1;
    int r = row0 + lr;
    if (r < NR) {
        int n = r / 10, t = r - (r / 10) * 10;
        size_t base = (size_t)n * FF + t * 64;
        if (side == 0) {
            float p0 = psi[n * 3], p1 = psi[n * 3 + 1], p2 = psi[n * 3 + 2];
#pragma unroll
            for (int i = 0; i < 8; ++i) {
                f16x8 a = *(const f16x8*)&h1[base + i * 8];
                f16x8 b = *(const f16x8*)&h2[base + i * 8];
                f16x8 c = *(const f16x8*)&h3[base + i * 8];
                f16x8 o;
#pragma unroll
                for (int j = 0; j < 8; ++j)
                    o[j] = (f16)(p0 * (float)a[j] + p1 * (float)b[j] + p2 * (float)c[j]);
                *(f16x8*)&As[lr][i * 8] = o;
            }
        } else {
#pragma unroll
            for (int i = 0; i < 8; ++i)
                *(f16x8*)&As[lr][64 + i * 8] = *(const f16x8*)&hneg[base + i * 8];
        }
    } else {
        f16x8 z = {};
#pragma unroll
        for (int i = 0; i < 8; ++i)
            *(f16x8*)&As[lr][side * 64 + i * 8] = z;
    }
    __syncthreads();

    int w = tid >> 6, l = tid & 63;
    int wr = w * 32;
    int lrow = l & 15;
    int lk = (l >> 4) * 8;
    f32x4 acc[2][4];
#pragma unroll
    for (int m = 0; m < 2; ++m)
#pragma unroll
        for (int n = 0; n < 4; ++n)
            acc[m][n] = (f32x4){0.f, 0.f, 0.f, 0.f};
#pragma unroll
    for (int ks = 0; ks < 4; ++ks) {
        f16x8 af[2], bf[4];
#pragma unroll
        for (int m = 0; m < 2; ++m)
            af[m] = *(const f16x8*)&As[wr + m * 16 + lrow][ks * 32 + lk];
#pragma unroll
        for (int n = 0; n < 4; ++n)
            bf[n] = *(const f16x8*)&Bs[n * 16 + lrow][ks * 32 + lk];
#pragma unroll
        for (int m = 0; m < 2; ++m)
#pragma unroll
            for (int n = 0; n < 4; ++n)
                acc[m][n] = __builtin_amdgcn_mfma_f32_16x16x32_f16(af[m], bf[n], acc[m][n], 0, 0, 0);
    }
    int orow = (l >> 4) * 4;
#pragma unroll
    for (int m = 0; m < 2; ++m) {
#pragma unroll
        for (int rr = 0; rr < 4; ++rr) {
            int ro = row0 + wr + m * 16 + orow + rr;
            if (ro < NR) {
#pragma unroll
                for (int n = 0; n < 4; ++n) {
                    int col = n * 16 + lrow;
                    out[(size_t)ro * 64 + col] = (f16)fmaxf(acc[m][n][rr] + gb[col], 0.f);
                }
            }
        }
    }
}

extern "C" void kernel_launch(void* const* d_in, const int* in_sizes, int n_in,
                              void* d_out, int out_size, void* d_ws, size_t ws_size,
                              hipStream_t stream)
{
    const float* x     = (const float*)d_in[0];
    const int*   ei    = (const int*)  d_in[1];
    const float* ea    = (const float*)d_in[2];
    const float* ndt   = (const float*)d_in[3];
    const float* tc1w1 = (const float*)d_in[4];
    const float* tc1b1 = (const float*)d_in[5];
    const float* tc1w2 = (const float*)d_in[6];
    const float* tc1b2 = (const float*)d_in[7];
    const float* Wpos  = (const float*)d_in[8];
    const float* bpos  = (const float*)d_in[9];
    const float* Wneg  = (const float*)d_in[10];
    const float* bneg  = (const float*)d_in[11];
    const float* greW  = (const float*)d_in[12];
    const float* greb  = (const float*)d_in[13];
    const float* psiW1 = (const float*)d_in[14];
    const float* psib1 = (const float*)d_in[15];
    const float* psiW2 = (const float*)d_in[16];
    const float* psib2 = (const float*)d_in[17];
    const float* tc2w1 = (const float*)d_in[18];
    const float* tc2b1 = (const float*)d_in[19];
    const float* tc2w2 = (const float*)d_in[20];
    const float* tc2b2 = (const float*)d_in[21];
    float* out = (float*)d_out;

    char* p = (char*)d_ws;
    f16*   xT    = (f16*)p;   p += (size_t)NN * CCH * TIN * 2;
    f16*   out0h = (f16*)p;   p += (size_t)NN * FF * 2;
    f16*   h1    = (f16*)p;   p += (size_t)NN * FF * 2;
    f16*   h2    = (f16*)p;   p += (size_t)NN * FF * 2;
    f16*   h3    = (f16*)p;   p += (size_t)NN * FF * 2;
    f16*   hneg  = (f16*)p;   p += (size_t)NN * FF * 2;
    f16*   Cb16  = (f16*)p;   p += (size_t)NN * FF * 2;
    f16*   Gbuf  = (f16*)p;   p += (size_t)NN * FF * 2;
    f16*   Wtp   = (f16*)p;   p += (size_t)FF * FF * 2;
    f16*   Wtn   = (f16*)p;   p += (size_t)FF * FF * 2;
    f16*   Wtmp  = (f16*)p;   p += (size_t)FF * FF * 2;
    f16*   gWt   = (f16*)p;   p += (size_t)128 * 64 * 2;
    f16*   Bw1   = (f16*)p;   p += (size_t)128 * 192 * 2;
    f16*   Bw2   = (f16*)p;   p += (size_t)128 * 192 * 2;
    float* psib  = (float*)p; p += (size_t)NN * 3 * 4;
    float* degp  = (float*)p; p += (size_t)NN * 4;
    float* degn  = (float*)p; p += (size_t)NN * 4;
    float* disp  = (float*)p; p += (size_t)NN * 4;
    float* disn  = (float*)p; p += (size_t)NN * 4;
    float* normp = (float*)p; p += (size_t)NE * 4;
    float* normn = (float*)p; p += (size_t)NE * 4;
    int* cnt     = (int*)p;   p += (size_t)NN * 4;
    int* rowptr  = (int*)p;   p += (size_t)(NN + 1) * 4;
    int* cursor  = (int*)p;   p += (size_t)NN * 4;
    int* colsrc  = (int*)p;   p += (size_t)NE * 4;

    (void)hipMemsetAsync(cnt, 0, NN * 4, stream);
    (void)hipMemsetAsync(cursor, 0, NN * 4, stream);
    (void)hipMemsetAsync(degp, 0, NN * 4, stream);
    (void)hipMemsetAsync(degn, 0, NN * 4, stream);

    k_xT<<<2500, 256, 0, stream>>>(x, xT);
    k_wconv<<<(128 * 192 + 255) / 256, 256, 0, stream>>>(tc1w1, tc1w2, Bw1);
    k_wconv<<<(128 * 192 + 255) / 256, 256, 0, stream>>>(tc2w1, tc2w2, Bw2);
    k_tcn1g<<<(NR + 127) / 128, 256, 0, stream>>>(xT, Bw1, tc1b1, tc1b2, out0h);
    k_psi<<<(NN + 255) / 256, 256, 0, stream>>>(ndt, psiW1, psib1, psiW2, psib2, psib);
    k_deg<<<(NE + 255) / 256, 256, 0, stream>>>(ei, ea, cnt, degp, degn);
    k_dis<<<(NN + 255) / 256, 256, 0, stream>>>(degp, degn, disp, disn);
    k_scan<<<1, 1024, 0, stream>>>(cnt, rowptr);
    k_fill<<<(NE + 255) / 256, 256, 0, stream>>>(ei, ea, rowptr, cursor, disp, disn,
                                                 colsrc, normp, normn);
    dim3 wgrid(20, 20);
    k_wsplit<<<wgrid, 256, 0, stream>>>(Wpos, Wtmp);
    k_perm<<<FF, 640, 0, stream>>>(Wtmp, Wtp);
    k_wsplit<<<wgrid, 256, 0, stream>>>(Wneg, Wtmp);
    k_perm<<<FF, 640, 0, stream>>>(Wtmp, Wtn);
    k_gwt<<<(128 * 64 + 255) / 256, 256, 0, stream>>>(greW, gWt);

    dim3 ggrid((NN + 127) / 128, FF / 64);
    // positive hops
    k_gemm16<<<ggrid, 256, 0, stream>>>(out0h, Wtp, Cb16, NN);
    k_agg<<<NN * 8, 64, 0, stream>>>(Cb16, rowptr, colsrc, normp, disp, bpos, h1);
    k_gemm16<<<ggrid, 256, 0, stream>>>(h1, Wtp, Cb16, NN);
    k_agg<<<NN * 8, 64, 0, stream>>>(Cb16, rowptr, colsrc, normp, disp, bpos, h2);
    k_gemm16<<<ggrid, 256, 0, stream>>>(h2, Wtp, Cb16, NN);
    k_agg<<<NN * 8, 64, 0, stream>>>(Cb16, rowptr, colsrc, normp, disp, bpos, h3);
    // negative branch
    k_gemm16<<<ggrid, 256, 0, stream>>>(out0h, Wtn, Cb16, NN);
    k_agg<<<NN * 8, 64, 0, stream>>>(Cb16, rowptr, colsrc, normn, disn, bneg, hneg);
    // GReTo channel mix (MFMA) + psi accumulation + relu -> f16
    k_greto2<<<(NR + 127) / 128, 256, 0, stream>>>(h1, h2, h3, hneg, psib, gWt, greb, Gbuf);
    // final gated TCN as direct GEMM
    k_tcn2g<<<(NR2 + 127) / 128, 256, 0, stream>>>(Gbuf, Bw2, tc2b1, tc2b2, out);
}

// Round 16
// 397.204 us; speedup vs baseline: 1.0987x; 1.0987x over previous
//
#include <hip/hip_runtime.h>
#include <math.h>

#define NN   10000   // nodes
#define NE   160000  // edges
#define CCH  64      // in/out channels
#define TIN  12      // input time steps
#define HCH  64      // hidden channels
#define TSP  10      // T - 2
#define FF   640     // H * TSP
#define TOUT 8       // TSP - 2
#define NR   (NN * TSP)    // 100000 rows for tcn1 / GCN / greto
#define NR2  (NN * TOUT)   // 80000 rows for tcn2

// GCN feature ordering: f' = t*64 + h (channel-contiguous rows)

typedef _Float16 f16;
typedef _Float16 f16x4 __attribute__((ext_vector_type(4)));
typedef _Float16 f16x8 __attribute__((ext_vector_type(8)));
typedef float f32x4 __attribute__((ext_vector_type(4)));

// async global->LDS, 16B per lane, wave-uniform LDS base + lane*16
#define GLD_LDS(gsrc, ldst) __builtin_amdgcn_global_load_lds( \
    (const __attribute__((address_space(1))) void*)(gsrc),    \
    (__attribute__((address_space(3))) void*)(ldst), 16, 0, 0)

// ---------------- x transpose: xT[n][t][c] = (f16)x[n][c][t] ----------------
__global__ __launch_bounds__(256) void k_xT(const float* __restrict__ x, f16* __restrict__ xT)
{
    __shared__ float xs[4][CCH * TIN];
    int node0 = blockIdx.x * 4;
    for (int i = threadIdx.x; i < 4 * CCH * TIN; i += 256) {
        int nn = i / (CCH * TIN), off = i % (CCH * TIN);
        int g = node0 + nn;
        xs[nn][off] = (g < NN) ? x[(size_t)g * CCH * TIN + off] : 0.f;
    }
    __syncthreads();
    for (int i = threadIdx.x; i < 4 * CCH * TIN; i += 256) {
        int nn = i / (CCH * TIN), off = i % (CCH * TIN);
        int t = off >> 6, c = off & 63;
        int g = node0 + nn;
        if (g < NN) xT[(size_t)g * (CCH * TIN) + off] = (f16)xs[nn][c * TIN + t];
    }
}

// ---------------- conv weights (both TCNs) -> Bw[o][k*64+ci] f16 ------------
__global__ void k_wconv2(const float* __restrict__ w1a, const float* __restrict__ w2a,
                         const float* __restrict__ w1b, const float* __restrict__ w2b,
                         f16* __restrict__ d1, f16* __restrict__ d2)
{
    int tid = blockIdx.x * 256 + threadIdx.x;
    const int half = 128 * 192;
    if (tid >= 2 * half) return;
    int which = tid / half, r = tid % half;
    const float* s1 = which ? w1b : w1a;
    const float* s2 = which ? w2b : w2a;
    f16* dst = which ? d2 : d1;
    int o = r / 192, j = r % 192;
    int k = j >> 6, ci = j & 63;
    const float* src = (o < 64) ? s1 : s2;
    dst[r] = (f16)src[((o & 63) * 64 + ci) * 3 + k];
}

// ---------------- TCN1 as direct GEMM, B staged in LDS ----------------------
__global__ __launch_bounds__(256) void k_tcn1g(const f16* __restrict__ A,   // xT [NN][768]
                                               const f16* __restrict__ Bw,
                                               const float* __restrict__ b1,
                                               const float* __restrict__ b2,
                                               f16* __restrict__ out)       // [NR][64] = f' order
{
    __shared__ f16 Bs[128][200];   // padded: row stride 100 dwords -> 2-way alias only
    int tid = threadIdx.x;
#pragma unroll
    for (int i = 0; i < 12; ++i) {
        int c = tid + i * 256;             // 3072 f16x8 chunks
        int row = c / 24, seg = (c % 24) * 8;
        *(f16x8*)&Bs[row][seg] = *(const f16x8*)&Bw[row * 192 + seg];
    }
    __syncthreads();

    int w = tid >> 6, l = tid & 63;
    int row0 = blockIdx.x * 128 + w * 32;
    int lrow = l & 15, lk = (l >> 4) * 8;

    size_t abase[2];
#pragma unroll
    for (int m = 0; m < 2; ++m) {
        int rr = row0 + m * 16 + lrow;
        int rc = (rr < NR) ? rr : NR - 1;
        int n = rc / 10, t = rc - n * 10;
        abase[m] = (size_t)n * 768 + t * 64 + lk;
    }
    f32x4 acc[2][8];
#pragma unroll
    for (int m = 0; m < 2; ++m)
#pragma unroll
        for (int n = 0; n < 8; ++n)
            acc[m][n] = (f32x4){0.f, 0.f, 0.f, 0.f};

#pragma unroll
    for (int ks = 0; ks < 6; ++ks) {
        f16x8 af[2], bf[8];
#pragma unroll
        for (int m = 0; m < 2; ++m)
            af[m] = *(const f16x8*)&A[abase[m] + ks * 32];
#pragma unroll
        for (int n = 0; n < 8; ++n)
            bf[n] = *(const f16x8*)&Bs[n * 16 + lrow][ks * 32 + lk];
#pragma unroll
        for (int m = 0; m < 2; ++m)
#pragma unroll
            for (int n = 0; n < 8; ++n)
                acc[m][n] = __builtin_amdgcn_mfma_f32_16x16x32_f16(af[m], bf[n], acc[m][n], 0, 0, 0);
    }
    int og = (l >> 4) * 4;
#pragma unroll
    for (int m = 0; m < 2; ++m) {
#pragma unroll
        for (int n = 0; n < 4; ++n) {
            int h = n * 16 + lrow;
            float bb1 = b1[h], bb2 = b2[h];
#pragma unroll
            for (int rr = 0; rr < 4; ++rr) {
                int R = row0 + m * 16 + og + rr;
                if (R < NR) {
                    float g1 = acc[m][n][rr] + bb1;
                    float g2 = acc[m][n + 4][rr] + bb2;
                    float e = __expf(2.f * g1);
                    float th = 1.f - 2.f / (e + 1.f);
                    float sg = 1.f / (1.f + __expf(-g2));
                    out[(size_t)R * 64 + h] = (f16)(th * sg);
                }
            }
        }
    }
}

// TCN2: A = Gbuf [NN][640] f16, rows r=n*8+t, slice at n*640+t*64; f32 out [N,64,8]
__global__ __launch_bounds__(256) void k_tcn2g(const f16* __restrict__ A,
                                               const f16* __restrict__ Bw,
                                               const float* __restrict__ b1,
                                               const float* __restrict__ b2,
                                               float* __restrict__ out)
{
    __shared__ f16 Bs[128][200];
    int tid = threadIdx.x;
#pragma unroll
    for (int i = 0; i < 12; ++i) {
        int c = tid + i * 256;
        int row = c / 24, seg = (c % 24) * 8;
        *(f16x8*)&Bs[row][seg] = *(const f16x8*)&Bw[row * 192 + seg];
    }
    __syncthreads();

    int w = tid >> 6, l = tid & 63;
    int row0 = blockIdx.x * 128 + w * 32;
    int lrow = l & 15, lk = (l >> 4) * 8;

    size_t abase[2];
#pragma unroll
    for (int m = 0; m < 2; ++m) {
        int rr = row0 + m * 16 + lrow;
        int rc = (rr < NR2) ? rr : NR2 - 1;
        int n = rc >> 3, t = rc & 7;
        abase[m] = (size_t)n * FF + t * 64 + lk;
    }
    f32x4 acc[2][8];
#pragma unroll
    for (int m = 0; m < 2; ++m)
#pragma unroll
        for (int n = 0; n < 8; ++n)
            acc[m][n] = (f32x4){0.f, 0.f, 0.f, 0.f};

#pragma unroll
    for (int ks = 0; ks < 6; ++ks) {
        f16x8 af[2], bf[8];
#pragma unroll
        for (int m = 0; m < 2; ++m)
            af[m] = *(const f16x8*)&A[abase[m] + ks * 32];
#pragma unroll
        for (int n = 0; n < 8; ++n)
            bf[n] = *(const f16x8*)&Bs[n * 16 + lrow][ks * 32 + lk];
#pragma unroll
        for (int m = 0; m < 2; ++m)
#pragma unroll
            for (int n = 0; n < 8; ++n)
                acc[m][n] = __builtin_amdgcn_mfma_f32_16x16x32_f16(af[m], bf[n], acc[m][n], 0, 0, 0);
    }
    int og = (l >> 4) * 4;
#pragma unroll
    for (int m = 0; m < 2; ++m) {
#pragma unroll
        for (int n = 0; n < 4; ++n) {
            int c = n * 16 + lrow;
            float bb1 = b1[c], bb2 = b2[c];
#pragma unroll
            for (int rr = 0; rr < 4; ++rr) {
                int R = row0 + m * 16 + og + rr;
                if (R < NR2) {
                    float g1 = acc[m][n][rr] + bb1;
                    float g2 = acc[m][n + 4][rr] + bb2;
                    float e = __expf(2.f * g1);
                    float th = 1.f - 2.f / (e + 1.f);
                    float sg = 1.f / (1.f + __expf(-g2));
                    int n2 = R >> 3, t2 = R & 7;
                    out[(size_t)n2 * (CCH * TOUT) + c * TOUT + t2] = th * sg;
                }
            }
        }
    }
}

// ---------------- psi MLP ---------------------------------------------------
__global__ void k_psi(const float* __restrict__ ND, const float* __restrict__ W1,
                      const float* __restrict__ b1, const float* __restrict__ W2,
                      const float* __restrict__ b2, float* __restrict__ psi)
{
    int n = blockIdx.x * blockDim.x + threadIdx.x;
    if (n >= NN) return;
    float d0 = ND[n * 3], d1 = ND[n * 3 + 1], d2 = ND[n * 3 + 2];
    float o0 = b2[0], o1 = b2[1], o2 = b2[2];
    for (int j = 0; j < 64; ++j) {
        float hv = d0 * W1[j] + d1 * W1[64 + j] + d2 * W1[128 + j] + b1[j];
        hv = fmaxf(hv, 0.f);
        o0 += hv * W2[j * 3 + 0];
        o1 += hv * W2[j * 3 + 1];
        o2 += hv * W2[j * 3 + 2];
    }
    psi[n * 3 + 0] = o0; psi[n * 3 + 1] = o1; psi[n * 3 + 2] = o2;
}

// ---------------- degree / counts -------------------------------------------
__global__ void k_deg(const int* __restrict__ ei, const float* __restrict__ ea,
                      int* __restrict__ cnt, float* __restrict__ degp, float* __restrict__ degn)
{
    int e = blockIdx.x * blockDim.x + threadIdx.x;
    if (e >= NE) return;
    int d = ei[NE + e];
    atomicAdd(&cnt[d], 1);
    atomicAdd(&degp[d], ea[e * 2 + 0] + 1.f);
    atomicAdd(&degn[d], ea[e * 2 + 1] + 1.f);
}

__global__ void k_dis(const float* __restrict__ degp, const float* __restrict__ degn,
                      float* __restrict__ disp, float* __restrict__ disn)
{
    int n = blockIdx.x * blockDim.x + threadIdx.x;
    if (n >= NN) return;
    disp[n] = 1.f / sqrtf(degp[n] + 1.f);
    disn[n] = 1.f / sqrtf(degn[n] + 1.f);
}

// ---------------- exclusive scan --------------------------------------------
__global__ __launch_bounds__(1024) void k_scan(const int* __restrict__ cnt, int* __restrict__ rowptr)
{
    __shared__ int buf[1024];
    __shared__ int carry;
    if (threadIdx.x == 0) carry = 0;
    __syncthreads();
    for (int base = 0; base < NN; base += 1024) {
        int i = base + threadIdx.x;
        int v = (i < NN) ? cnt[i] : 0;
        buf[threadIdx.x] = v;
        __syncthreads();
        for (int off = 1; off < 1024; off <<= 1) {
            int t = (threadIdx.x >= (unsigned)off) ? buf[threadIdx.x - off] : 0;
            __syncthreads();
            buf[threadIdx.x] += t;
            __syncthreads();
        }
        if (i < NN) rowptr[i] = carry + buf[threadIdx.x] - v;
        __syncthreads();
        if (threadIdx.x == 0) carry += buf[1023];
        __syncthreads();
    }
    if (threadIdx.x == 0) rowptr[NN] = carry;
}

// ---------------- CSR fill ---------------------------------------------------
__global__ void k_fill(const int* __restrict__ ei, const float* __restrict__ ea,
                       const int* __restrict__ rowptr, int* __restrict__ cursor,
                       const float* __restrict__ disp, const float* __restrict__ disn,
                       int* __restrict__ colsrc, float* __restrict__ normp, float* __restrict__ normn)
{
    int e = blockIdx.x * blockDim.x + threadIdx.x;
    if (e >= NE) return;
    int s = ei[e], d = ei[NE + e];
    int slot = atomicAdd(&cursor[d], 1);
    int idx = rowptr[d] + slot;
    colsrc[idx] = s;
    normp[idx] = disp[s] * (ea[e * 2 + 0] + 1.f) * disp[d];
    normn[idx] = disn[s] * (ea[e * 2 + 1] + 1.f) * disn[d];
}

// ---------------- W transpose+cast (batched pos/neg via z) ------------------
__global__ __launch_bounds__(256) void k_wsplit2(const float* __restrict__ Wa,
                                                 const float* __restrict__ Wb,
                                                 f16* __restrict__ Wt)   // [2][FF*FF]
{
    __shared__ float t[32][33];
    const float* W = blockIdx.z ? Wb : Wa;
    f16* dst = Wt + (size_t)blockIdx.z * FF * FF;
    int bx = blockIdx.x * 32;
    int by = blockIdx.y * 32;
    int tx = threadIdx.x & 31, ty = threadIdx.x >> 5;
#pragma unroll
    for (int j = 0; j < 4; ++j)
        t[ty + j * 8][tx] = W[(size_t)(bx + ty + j * 8) * 640 + by + tx];
    __syncthreads();
#pragma unroll
    for (int j = 0; j < 4; ++j)
        dst[(size_t)(by + ty + j * 8) * 640 + bx + tx] = (f16)t[tx][ty + j * 8];
}

// ---------------- permute rows+cols to f' order (batched via z) -------------
__global__ __launch_bounds__(640) void k_perm2(const f16* __restrict__ Wt0,
                                               f16* __restrict__ Wp, f16* __restrict__ Wn)
{
    __shared__ f16 row[FF];
    const f16* src = Wt0 + (size_t)blockIdx.z * FF * FF;
    f16* dst = blockIdx.z ? Wn : Wp;
    int np = blockIdx.x;
    int n = (np & 63) * 10 + (np >> 6);
    int tid = threadIdx.x;
    row[tid] = src[(size_t)n * FF + tid];
    __syncthreads();
    int k = (tid & 63) * 10 + (tid >> 6);
    dst[(size_t)np * FF + tid] = row[k];
}

// ---------------- gW transpose: gWt[d][c] = (f16)gW[c][d] -------------------
__global__ void k_gwt(const float* __restrict__ gW, f16* __restrict__ gWt)
{
    int tid = blockIdx.x * 256 + threadIdx.x;
    if (tid >= 128 * 64) return;
    int c = tid >> 6, d = tid & 63;
    gWt[d * 128 + c] = (f16)gW[tid];
}

// ---------------- f16 MFMA GEMM with global_load_lds staging ----------------
// C[M,640] = A[M,640] @ Bt^T (f16 out); tile 128x64, BK=32, 4 waves
// grid = (col blocks = 10, row blocks = 79): consecutive blocks share an
// A row-panel -> A stays L2-hot instead of being re-streamed 10x.
__global__ __launch_bounds__(256) void k_gemm16(const f16* __restrict__ A,
                                                const f16* __restrict__ Bt,
                                                f16* __restrict__ C, int M)
{
    __shared__ f16 As[128 * 32];   // linear [row][32]
    __shared__ f16 Bs[64 * 32];
    int tid = threadIdx.x;
    int row0 = blockIdx.y * 128;
    int col0 = blockIdx.x * 64;
    int w = tid >> 6, l = tid & 63;
    int wr = (w >> 1) * 64;
    int wc = (w & 1) * 32;
    int lrow = l & 15;
    int lk = (l >> 4) * 8;

    int arow = w * 32 + (l >> 2);
    int brow = w * 16 + (l >> 2);
    int seg  = (l & 3) * 8;

    f32x4 acc[4][2];
#pragma unroll
    for (int m = 0; m < 4; ++m)
#pragma unroll
        for (int n = 0; n < 2; ++n)
            acc[m][n] = (f32x4){0.f, 0.f, 0.f, 0.f};

    for (int k0 = 0; k0 < FF; k0 += 32) {
        __syncthreads();
        GLD_LDS(&A[(size_t)(row0 + arow) * FF + k0 + seg],       &As[w * 1024]);
        GLD_LDS(&A[(size_t)(row0 + arow + 16) * FF + k0 + seg],  &As[w * 1024 + 512]);
        GLD_LDS(&Bt[(size_t)(col0 + brow) * FF + k0 + seg],      &Bs[w * 512]);
        __syncthreads();
        f16x8 af[4], bf[2];
#pragma unroll
        for (int m = 0; m < 4; ++m)
            af[m] = *(const f16x8*)&As[(wr + m * 16 + lrow) * 32 + lk];
#pragma unroll
        for (int n = 0; n < 2; ++n)
            bf[n] = *(const f16x8*)&Bs[(wc + n * 16 + lrow) * 32 + lk];
#pragma unroll
        for (int m = 0; m < 4; ++m)
#pragma unroll
            for (int n = 0; n < 2; ++n)
                acc[m][n] = __builtin_amdgcn_mfma_f32_16x16x32_f16(af[m], bf[n], acc[m][n], 0, 0, 0);
    }
    int orow = (l >> 4) * 4;
#pragma unroll
    for (int m = 0; m < 4; ++m) {
#pragma unroll
        for (int r = 0; r < 4; ++r) {
            int rr = row0 + wr + m * 16 + orow + r;
            if (rr < M) {
#pragma unroll
                for (int n = 0; n < 2; ++n)
                    C[(size_t)rr * FF + col0 + wc + n * 16 + lrow] = (f16)acc[m][n][r];
            }
        }
    }
}

// ---------------- GCN aggregate (LDS-preloaded indices, f16x4 lanes) --------
// 192 threads; lanes 0..159 gather 4 cols each (8B loads)
__global__ __launch_bounds__(192) void k_agg(const f16* __restrict__ hsrc,
                      const int* __restrict__ rowptr, const int* __restrict__ colsrc,
                      const float* __restrict__ enorm, const float* __restrict__ dis,
                      const float* __restrict__ bias, f16* __restrict__ hout)
{
    __shared__ int   s_idx[128];
    __shared__ float s_w[128];
    int d = blockIdx.x;
    int lane = threadIdx.x;
    int c0 = lane * 4;
    bool act = lane < 160;
    float v0 = 0.f, v1 = 0.f, v2 = 0.f, v3 = 0.f;
    if (act) {
        float selfw = dis[d] * dis[d];
        f16x4 self = *(const f16x4*)&hsrc[(size_t)d * FF + c0];
        v0 = selfw * (float)self[0];
        v1 = selfw * (float)self[1];
        v2 = selfw * (float)self[2];
        v3 = selfw * (float)self[3];
    }
    int beg = rowptr[d], end = rowptr[d + 1];
    for (int base = beg; base < end; base += 128) {
        int cnt = (end - base < 128) ? (end - base) : 128;
        __syncthreads();
        for (int j = lane; j < cnt; j += 192) {
            s_idx[j] = colsrc[base + j];
            s_w[j]   = enorm[base + j];
        }
        __syncthreads();
        if (act) {
            for (int i = 0; i < cnt; ++i) {
                f16x4 p = *(const f16x4*)&hsrc[(size_t)s_idx[i] * FF + c0];
                float w = s_w[i];
                v0 += w * (float)p[0];
                v1 += w * (float)p[1];
                v2 += w * (float)p[2];
                v3 += w * (float)p[3];
            }
        }
    }
    if (act) {
        f16x4 o;
        float vv[4] = {v0, v1, v2, v3};
#pragma unroll
        for (int j = 0; j < 4; ++j) {
            int c = c0 + j;
            o[j] = (f16)fmaxf(vv[j] + bias[(c & 63) * 10 + (c >> 6)], 0.f);
        }
        *(f16x4*)&hout[(size_t)d * FF + c0] = o;
    }
}

// ---------------- GReTo mix as MFMA GEMM (f16 out) --------------------------
__global__ __launch_bounds__(256) void k_greto2(const f16* __restrict__ h1,
                        const f16* __restrict__ h2, const f16* __restrict__ h3,
                        const f16* __restrict__ hneg, const float* __restrict__ psi,
                        const f16* __restrict__ gWt, const float* __restrict__ gb,
                        f16* __restrict__ out)
{
    __shared__ f16 As[128][132];
    __shared__ f16 Bs[64][132];
    int tid = threadIdx.x;
    int row0 = blockIdx.x * 128;

    for (int cb = tid; cb < 1024; cb += 256) {
        int d = cb >> 4, seg = (cb & 15) * 8;
        *(f16x8*)&Bs[d][seg] = *(const f16x8*)&gWt[d * 128 + seg];
    }
    int lr = tid >> 1, side = tid & 1;
    int r = row0 + lr;
    if (r < NR) {
        int n = r / 10, t = r - (r / 10) * 10;
        size_t base = (size_t)n * FF + t * 64;
        if (side == 0) {
            float p0 = psi[n * 3], p1 = psi[n * 3 + 1], p2 = psi[n * 3 + 2];
#pragma unroll
            for (int i = 0; i < 8; ++i) {
                f16x8 a = *(const f16x8*)&h1[base + i * 8];
                f16x8 b = *(const f16x8*)&h2[base + i * 8];
                f16x8 c = *(const f16x8*)&h3[base + i * 8];
                f16x8 o;
#pragma unroll
                for (int j = 0; j < 8; ++j)
                    o[j] = (f16)(p0 * (float)a[j] + p1 * (float)b[j] + p2 * (float)c[j]);
                *(f16x8*)&As[lr][i * 8] = o;
            }
        } else {
#pragma unroll
            for (int i = 0; i < 8; ++i)
                *(f16x8*)&As[lr][64 + i * 8] = *(const f16x8*)&hneg[base + i * 8];
        }
    } else {
        f16x8 z = {};
#pragma unroll
        for (int i = 0; i < 8; ++i)
            *(f16x8*)&As[lr][side * 64 + i * 8] = z;
    }
    __syncthreads();

    int w = tid >> 6, l = tid & 63;
    int wr = w * 32;
    int lrow = l & 15;
    int lk = (l >> 4) * 8;
    f32x4 acc[2][4];
#pragma unroll
    for (int m = 0; m < 2; ++m)
#pragma unroll
        for (int n = 0; n < 4; ++n)
            acc[m][n] = (f32x4){0.f, 0.f, 0.f, 0.f};
#pragma unroll
    for (int ks = 0; ks < 4; ++ks) {
        f16x8 af[2], bf[4];
#pragma unroll
        for (int m = 0; m < 2; ++m)
            af[m] = *(const f16x8*)&As[wr + m * 16 + lrow][ks * 32 + lk];
#pragma unroll
        for (int n = 0; n < 4; ++n)
            bf[n] = *(const f16x8*)&Bs[n * 16 + lrow][ks * 32 + lk];
#pragma unroll
        for (int m = 0; m < 2; ++m)
#pragma unroll
            for (int n = 0; n < 4; ++n)
                acc[m][n] = __builtin_amdgcn_mfma_f32_16x16x32_f16(af[m], bf[n], acc[m][n], 0, 0, 0);
    }
    int orow = (l >> 4) * 4;
#pragma unroll
    for (int m = 0; m < 2; ++m) {
#pragma unroll
        for (int rr = 0; rr < 4; ++rr) {
            int ro = row0 + wr + m * 16 + orow + rr;
            if (ro < NR) {
#pragma unroll
                for (int n = 0; n < 4; ++n) {
                    int col = n * 16 + lrow;
                    out[(size_t)ro * 64 + col] = (f16)fmaxf(acc[m][n][rr] + gb[col], 0.f);
                }
            }
        }
    }
}

extern "C" void kernel_launch(void* const* d_in, const int* in_sizes, int n_in,
                              void* d_out, int out_size, void* d_ws, size_t ws_size,
                              hipStream_t stream)
{
    const float* x     = (const float*)d_in[0];
    const int*   ei    = (const int*)  d_in[1];
    const float* ea    = (const float*)d_in[2];
    const float* ndt   = (const float*)d_in[3];
    const float* tc1w1 = (const float*)d_in[4];
    const float* tc1b1 = (const float*)d_in[5];
    const float* tc1w2 = (const float*)d_in[6];
    const float* tc1b2 = (const float*)d_in[7];
    const float* Wpos  = (const float*)d_in[8];
    const float* bpos  = (const float*)d_in[9];
    const float* Wneg  = (const float*)d_in[10];
    const float* bneg  = (const float*)d_in[11];
    const float* greW  = (const float*)d_in[12];
    const float* greb  = (const float*)d_in[13];
    const float* psiW1 = (const float*)d_in[14];
    const float* psib1 = (const float*)d_in[15];
    const float* psiW2 = (const float*)d_in[16];
    const float* psib2 = (const float*)d_in[17];
    const float* tc2w1 = (const float*)d_in[18];
    const float* tc2b1 = (const float*)d_in[19];
    const float* tc2w2 = (const float*)d_in[20];
    const float* tc2b2 = (const float*)d_in[21];
    float* out = (float*)d_out;

    char* p = (char*)d_ws;
    // zero region (one memset): cnt, cursor, degp, degn
    int*   cnt   = (int*)p;   p += (size_t)NN * 4;
    int*   cursor= (int*)p;   p += (size_t)NN * 4;
    float* degp  = (float*)p; p += (size_t)NN * 4;
    float* degn  = (float*)p; p += (size_t)NN * 4;
    f16*   xT    = (f16*)p;   p += (size_t)NN * CCH * TIN * 2;
    f16*   out0h = (f16*)p;   p += (size_t)NN * FF * 2;
    f16*   h1    = (f16*)p;   p += (size_t)NN * FF * 2;
    f16*   h2    = (f16*)p;   p += (size_t)NN * FF * 2;
    f16*   h3    = (f16*)p;   p += (size_t)NN * FF * 2;
    f16*   hneg  = (f16*)p;   p += (size_t)NN * FF * 2;
    f16*   Cb16  = (f16*)p;   p += (size_t)NN * FF * 2;
    f16*   Gbuf  = (f16*)p;   p += (size_t)NN * FF * 2;
    f16*   Wtp   = (f16*)p;   p += (size_t)FF * FF * 2;
    f16*   Wtn   = (f16*)p;   p += (size_t)FF * FF * 2;
    f16*   Wtmp  = (f16*)p;   p += (size_t)2 * FF * FF * 2;
    f16*   gWt   = (f16*)p;   p += (size_t)128 * 64 * 2;
    f16*   Bw1   = (f16*)p;   p += (size_t)128 * 192 * 2;
    f16*   Bw2   = (f16*)p;   p += (size_t)128 * 192 * 2;
    float* psib  = (float*)p; p += (size_t)NN * 3 * 4;
    float* disp  = (float*)p; p += (size_t)NN * 4;
    float* disn  = (float*)p; p += (size_t)NN * 4;
    float* normp = (float*)p; p += (size_t)NE * 4;
    float* normn = (float*)p; p += (size_t)NE * 4;
    int* rowptr  = (int*)p;   p += (size_t)(NN + 1) * 4;
    int* colsrc  = (int*)p;   p += (size_t)NE * 4;

    (void)hipMemsetAsync(cnt, 0, (size_t)4 * NN * 4, stream);   // cnt+cursor+degp+degn

    k_xT<<<2500, 256, 0, stream>>>(x, xT);
    k_wconv2<<<(2 * 128 * 192 + 255) / 256, 256, 0, stream>>>(tc1w1, tc1w2, tc2w1, tc2w2, Bw1, Bw2);
    k_tcn1g<<<(NR + 127) / 128, 256, 0, stream>>>(xT, Bw1, tc1b1, tc1b2, out0h);
    k_psi<<<(NN + 255) / 256, 256, 0, stream>>>(ndt, psiW1, psib1, psiW2, psib2, psib);
    k_deg<<<(NE + 255) / 256, 256, 0, stream>>>(ei, ea, cnt, degp, degn);
    k_dis<<<(NN + 255) / 256, 256, 0, stream>>>(degp, degn, disp, disn);
    k_scan<<<1, 1024, 0, stream>>>(cnt, rowptr);
    k_fill<<<(NE + 255) / 256, 256, 0, stream>>>(ei, ea, rowptr, cursor, disp, disn,
                                                 colsrc, normp, normn);
    dim3 wgrid(20, 20, 2);
    k_wsplit2<<<wgrid, 256, 0, stream>>>(Wpos, Wneg, Wtmp);
    dim3 pgrid(FF, 1, 2);
    k_perm2<<<pgrid, 640, 0, stream>>>(Wtmp, Wtp, Wtn);
    k_gwt<<<(128 * 64 + 255) / 256, 256, 0, stream>>>(greW, gWt);

    dim3 ggrid(FF / 64, (NN + 127) / 128);   // col-major-ish: A panel reuse
    // positive hops
    k_gemm16<<<ggrid, 256, 0, stream>>>(out0h, Wtp, Cb16, NN);
    k_agg<<<NN, 192, 0, stream>>>(Cb16, rowptr, colsrc, normp, disp, bpos, h1);
    k_gemm16<<<ggrid, 256, 0, stream>>>(h1, Wtp, Cb16, NN);
    k_agg<<<NN, 192, 0, stream>>>(Cb16, rowptr, colsrc, normp, disp, bpos, h2);
    k_gemm16<<<ggrid, 256, 0, stream>>>(h2, Wtp, Cb16, NN);
    k_agg<<<NN, 192, 0, stream>>>(Cb16, rowptr, colsrc, normp, disp, bpos, h3);
    // negative branch
    k_gemm16<<<ggrid, 256, 0, stream>>>(out0h, Wtn, Cb16, NN);
    k_agg<<<NN, 192, 0, stream>>>(Cb16, rowptr, colsrc, normn, disn, bneg, hneg);
    // GReTo channel mix (MFMA) + psi accumulation + relu -> f16
    k_greto2<<<(NR + 127) / 128, 256, 0, stream>>>(h1, h2, h3, hneg, psib, gWt, greb, Gbuf);
    // final gated TCN as direct GEMM
    k_tcn2g<<<(NR2 + 127) / 128, 256, 0, stream>>>(Gbuf, Bw2, tc2b1, tc2b2, out);
}

// Round 17
// 346.368 us; speedup vs baseline: 1.2600x; 1.1468x over previous
//
#include <hip/hip_runtime.h>
#include <math.h>

#define NN   10000   // nodes
#define NE   160000  // edges
#define CCH  64      // in/out channels
#define TIN  12      // input time steps
#define HCH  64      // hidden channels
#define TSP  10      // T - 2
#define FF   640     // H * TSP
#define TOUT 8       // TSP - 2
#define NR   (NN * TSP)    // 100000 rows
#define NR2  (NN * TOUT)   // 80000 rows

typedef _Float16 f16;
typedef _Float16 f16x8 __attribute__((ext_vector_type(8)));
typedef float f32x4 __attribute__((ext_vector_type(4)));

#define GLD_LDS(gsrc, ldst) __builtin_amdgcn_global_load_lds( \
    (const __attribute__((address_space(1))) void*)(gsrc),    \
    (__attribute__((address_space(3))) void*)(ldst), 16, 0, 0)

// ---------------- mega prep: xT | wconv | psi | gwt | deg | wsplit ----------
// role boundaries (block counts): xT 2500 | wconv 192 | psi 40 | gwt 32 |
// deg 625 | wsplit 800  => total 4189
#define PB_XT   2500
#define PB_WC   (PB_XT + 192)
#define PB_PSI  (PB_WC + 40)
#define PB_GWT  (PB_PSI + 32)
#define PB_DEG  (PB_GWT + 625)
#define PB_WS   (PB_DEG + 800)

__global__ __launch_bounds__(256) void k_prep(
    const float* __restrict__ x, f16* __restrict__ xT,
    const float* __restrict__ tc1w1, const float* __restrict__ tc1w2,
    const float* __restrict__ tc2w1, const float* __restrict__ tc2w2,
    f16* __restrict__ Bw1, f16* __restrict__ Bw2,
    const float* __restrict__ ND, const float* __restrict__ pW1,
    const float* __restrict__ pb1, const float* __restrict__ pW2,
    const float* __restrict__ pb2, float* __restrict__ psi,
    const float* __restrict__ gW, f16* __restrict__ gWt,
    const int* __restrict__ ei, const float* __restrict__ ea,
    int* __restrict__ cnt, float* __restrict__ degp, float* __restrict__ degn,
    const float* __restrict__ Wpos, const float* __restrict__ Wneg,
    f16* __restrict__ Wtmp)
{
    __shared__ float smem[3072];
    int blk = blockIdx.x;
    int tid = threadIdx.x;

    if (blk < PB_XT) {                       // ---- x transpose ----
        float (*xs)[CCH * TIN] = (float(*)[CCH * TIN])smem;
        int node0 = blk * 4;
        for (int i = tid; i < 4 * CCH * TIN; i += 256) {
            int nn = i / (CCH * TIN), off = i % (CCH * TIN);
            int g = node0 + nn;
            xs[nn][off] = (g < NN) ? x[(size_t)g * CCH * TIN + off] : 0.f;
        }
        __syncthreads();
        for (int i = tid; i < 4 * CCH * TIN; i += 256) {
            int nn = i / (CCH * TIN), off = i % (CCH * TIN);
            int t = off >> 6, c = off & 63;
            int g = node0 + nn;
            if (g < NN) xT[(size_t)g * (CCH * TIN) + off] = (f16)xs[nn][c * TIN + t];
        }
    } else if (blk < PB_WC) {                // ---- conv weights ----
        int t2 = (blk - PB_XT) * 256 + tid;
        const int half = 128 * 192;
        if (t2 < 2 * half) {
            int which = t2 / half, r = t2 % half;
            const float* s1 = which ? tc2w1 : tc1w1;
            const float* s2 = which ? tc2w2 : tc1w2;
            f16* dst = which ? Bw2 : Bw1;
            int o = r / 192, j = r % 192;
            int k = j >> 6, ci = j & 63;
            const float* src = (o < 64) ? s1 : s2;
            dst[r] = (f16)src[((o & 63) * 64 + ci) * 3 + k];
        }
    } else if (blk < PB_PSI) {               // ---- psi MLP ----
        int n = (blk - PB_WC) * 256 + tid;
        if (n < NN) {
            float d0 = ND[n * 3], d1 = ND[n * 3 + 1], d2 = ND[n * 3 + 2];
            float o0 = pb2[0], o1 = pb2[1], o2 = pb2[2];
            for (int j = 0; j < 64; ++j) {
                float hv = d0 * pW1[j] + d1 * pW1[64 + j] + d2 * pW1[128 + j] + pb1[j];
                hv = fmaxf(hv, 0.f);
                o0 += hv * pW2[j * 3 + 0];
                o1 += hv * pW2[j * 3 + 1];
                o2 += hv * pW2[j * 3 + 2];
            }
            psi[n * 3 + 0] = o0; psi[n * 3 + 1] = o1; psi[n * 3 + 2] = o2;
        }
    } else if (blk < PB_GWT) {               // ---- gW transpose ----
        int t2 = (blk - PB_PSI) * 256 + tid;
        if (t2 < 128 * 64) {
            int c = t2 >> 6, d = t2 & 63;
            gWt[d * 128 + c] = (f16)gW[t2];
        }
    } else if (blk < PB_DEG) {               // ---- degree ----
        int e = (blk - PB_GWT) * 256 + tid;
        if (e < NE) {
            int d = ei[NE + e];
            atomicAdd(&cnt[d], 1);
            atomicAdd(&degp[d], ea[e * 2 + 0] + 1.f);
            atomicAdd(&degn[d], ea[e * 2 + 1] + 1.f);
        }
    } else {                                 // ---- W transpose+cast ----
        float (*tt)[33] = (float(*)[33])smem;
        int rel = blk - PB_DEG;
        int z = rel / 400, r2 = rel % 400;
        const float* W = z ? Wneg : Wpos;
        f16* dst = Wtmp + (size_t)z * FF * FF;
        int bx = (r2 / 20) * 32;
        int by = (r2 % 20) * 32;
        int tx = tid & 31, ty = tid >> 5;
#pragma unroll
        for (int j = 0; j < 4; ++j)
            tt[ty + j * 8][tx] = W[(size_t)(bx + ty + j * 8) * 640 + by + tx];
        __syncthreads();
#pragma unroll
        for (int j = 0; j < 4; ++j)
            dst[(size_t)(by + ty + j * 8) * 640 + bx + tx] = (f16)tt[tx][ty + j * 8];
    }
}

// ---------------- TCN1 as direct GEMM, B staged in LDS ----------------------
__global__ __launch_bounds__(256) void k_tcn1g(const f16* __restrict__ A,
                                               const f16* __restrict__ Bw,
                                               const float* __restrict__ b1,
                                               const float* __restrict__ b2,
                                               f16* __restrict__ out)
{
    __shared__ f16 Bs[128][200];
    int tid = threadIdx.x;
#pragma unroll
    for (int i = 0; i < 12; ++i) {
        int c = tid + i * 256;
        int row = c / 24, seg = (c % 24) * 8;
        *(f16x8*)&Bs[row][seg] = *(const f16x8*)&Bw[row * 192 + seg];
    }
    __syncthreads();

    int w = tid >> 6, l = tid & 63;
    int row0 = blockIdx.x * 128 + w * 32;
    int lrow = l & 15, lk = (l >> 4) * 8;

    size_t abase[2];
#pragma unroll
    for (int m = 0; m < 2; ++m) {
        int rr = row0 + m * 16 + lrow;
        int rc = (rr < NR) ? rr : NR - 1;
        int n = rc / 10, t = rc - n * 10;
        abase[m] = (size_t)n * 768 + t * 64 + lk;
    }
    f32x4 acc[2][8];
#pragma unroll
    for (int m = 0; m < 2; ++m)
#pragma unroll
        for (int n = 0; n < 8; ++n)
            acc[m][n] = (f32x4){0.f, 0.f, 0.f, 0.f};

#pragma unroll
    for (int ks = 0; ks < 6; ++ks) {
        f16x8 af[2], bf[8];
#pragma unroll
        for (int m = 0; m < 2; ++m)
            af[m] = *(const f16x8*)&A[abase[m] + ks * 32];
#pragma unroll
        for (int n = 0; n < 8; ++n)
            bf[n] = *(const f16x8*)&Bs[n * 16 + lrow][ks * 32 + lk];
#pragma unroll
        for (int m = 0; m < 2; ++m)
#pragma unroll
            for (int n = 0; n < 8; ++n)
                acc[m][n] = __builtin_amdgcn_mfma_f32_16x16x32_f16(af[m], bf[n], acc[m][n], 0, 0, 0);
    }
    int og = (l >> 4) * 4;
#pragma unroll
    for (int m = 0; m < 2; ++m) {
#pragma unroll
        for (int n = 0; n < 4; ++n) {
            int h = n * 16 + lrow;
            float bb1 = b1[h], bb2 = b2[h];
#pragma unroll
            for (int rr = 0; rr < 4; ++rr) {
                int R = row0 + m * 16 + og + rr;
                if (R < NR) {
                    float g1 = acc[m][n][rr] + bb1;
                    float g2 = acc[m][n + 4][rr] + bb2;
                    float e = __expf(2.f * g1);
                    float th = 1.f - 2.f / (e + 1.f);
                    float sg = 1.f / (1.f + __expf(-g2));
                    out[(size_t)R * 64 + h] = (f16)(th * sg);
                }
            }
        }
    }
}

// TCN2
__global__ __launch_bounds__(256) void k_tcn2g(const f16* __restrict__ A,
                                               const f16* __restrict__ Bw,
                                               const float* __restrict__ b1,
                                               const float* __restrict__ b2,
                                               float* __restrict__ out)
{
    __shared__ f16 Bs[128][200];
    int tid = threadIdx.x;
#pragma unroll
    for (int i = 0; i < 12; ++i) {
        int c = tid + i * 256;
        int row = c / 24, seg = (c % 24) * 8;
        *(f16x8*)&Bs[row][seg] = *(const f16x8*)&Bw[row * 192 + seg];
    }
    __syncthreads();

    int w = tid >> 6, l = tid & 63;
    int row0 = blockIdx.x * 128 + w * 32;
    int lrow = l & 15, lk = (l >> 4) * 8;

    size_t abase[2];
#pragma unroll
    for (int m = 0; m < 2; ++m) {
        int rr = row0 + m * 16 + lrow;
        int rc = (rr < NR2) ? rr : NR2 - 1;
        int n = rc >> 3, t = rc & 7;
        abase[m] = (size_t)n * FF + t * 64 + lk;
    }
    f32x4 acc[2][8];
#pragma unroll
    for (int m = 0; m < 2; ++m)
#pragma unroll
        for (int n = 0; n < 8; ++n)
            acc[m][n] = (f32x4){0.f, 0.f, 0.f, 0.f};

#pragma unroll
    for (int ks = 0; ks < 6; ++ks) {
        f16x8 af[2], bf[8];
#pragma unroll
        for (int m = 0; m < 2; ++m)
            af[m] = *(const f16x8*)&A[abase[m] + ks * 32];
#pragma unroll
        for (int n = 0; n < 8; ++n)
            bf[n] = *(const f16x8*)&Bs[n * 16 + lrow][ks * 32 + lk];
#pragma unroll
        for (int m = 0; m < 2; ++m)
#pragma unroll
            for (int n = 0; n < 8; ++n)
                acc[m][n] = __builtin_amdgcn_mfma_f32_16x16x32_f16(af[m], bf[n], acc[m][n], 0, 0, 0);
    }
    int og = (l >> 4) * 4;
#pragma unroll
    for (int m = 0; m < 2; ++m) {
#pragma unroll
        for (int n = 0; n < 4; ++n) {
            int c = n * 16 + lrow;
            float bb1 = b1[c], bb2 = b2[c];
#pragma unroll
            for (int rr = 0; rr < 4; ++rr) {
                int R = row0 + m * 16 + og + rr;
                if (R < NR2) {
                    float g1 = acc[m][n][rr] + bb1;
                    float g2 = acc[m][n + 4][rr] + bb2;
                    float e = __expf(2.f * g1);
                    float th = 1.f - 2.f / (e + 1.f);
                    float sg = 1.f / (1.f + __expf(-g2));
                    int n2 = R >> 3, t2 = R & 7;
                    out[(size_t)n2 * (CCH * TOUT) + c * TOUT + t2] = th * sg;
                }
            }
        }
    }
}

// ---------------- scan (thread-coarsened) + dis fold ------------------------
__global__ __launch_bounds__(1024) void k_scan(const int* __restrict__ cnt,
                      int* __restrict__ rowptr,
                      const float* __restrict__ degp, const float* __restrict__ degn,
                      float* __restrict__ disp, float* __restrict__ disn)
{
    int tid = threadIdx.x;
    for (int i = tid; i < NN; i += 1024) {
        disp[i] = 1.f / sqrtf(degp[i] + 1.f);
        disn[i] = 1.f / sqrtf(degn[i] + 1.f);
    }
    __shared__ int part[1024];
    int base = tid * 10;
    int loc[10];
    int sum = 0;
    if (tid < 1000) {
#pragma unroll
        for (int j = 0; j < 10; ++j) { loc[j] = sum; sum += cnt[base + j]; }
    }
    part[tid] = (tid < 1000) ? sum : 0;
    __syncthreads();
    for (int off = 1; off < 1024; off <<= 1) {
        int t = (tid >= off) ? part[tid - off] : 0;
        __syncthreads();
        part[tid] += t;
        __syncthreads();
    }
    int prefix = (tid > 0) ? part[tid - 1] : 0;
    if (tid < 1000) {
#pragma unroll
        for (int j = 0; j < 10; ++j) rowptr[base + j] = prefix + loc[j];
    }
    if (tid == 0) rowptr[NN] = part[1023];
}

// ---------------- CSR fill ---------------------------------------------------
__global__ void k_fill(const int* __restrict__ ei, const float* __restrict__ ea,
                       const int* __restrict__ rowptr, int* __restrict__ cursor,
                       const float* __restrict__ disp, const float* __restrict__ disn,
                       int* __restrict__ colsrc, float* __restrict__ normp, float* __restrict__ normn)
{
    int e = blockIdx.x * blockDim.x + threadIdx.x;
    if (e >= NE) return;
    int s = ei[e], d = ei[NE + e];
    int slot = atomicAdd(&cursor[d], 1);
    int idx = rowptr[d] + slot;
    colsrc[idx] = s;
    normp[idx] = disp[s] * (ea[e * 2 + 0] + 1.f) * disp[d];
    normn[idx] = disn[s] * (ea[e * 2 + 1] + 1.f) * disn[d];
}

// ---------------- permute rows+cols to f' order (batched via z) -------------
__global__ __launch_bounds__(640) void k_perm2(const f16* __restrict__ Wt0,
                                               f16* __restrict__ Wp, f16* __restrict__ Wn)
{
    __shared__ f16 row[FF];
    const f16* src = Wt0 + (size_t)blockIdx.z * FF * FF;
    f16* dst = blockIdx.z ? Wn : Wp;
    int np = blockIdx.x;
    int n = (np & 63) * 10 + (np >> 6);
    int tid = threadIdx.x;
    row[tid] = src[(size_t)n * FF + tid];
    __syncthreads();
    int k = (tid & 63) * 10 + (tid >> 6);
    dst[(size_t)np * FF + tid] = row[k];
}

// ---------------- f16 MFMA GEMM with global_load_lds staging ----------------
__global__ __launch_bounds__(256) void k_gemm16(const f16* __restrict__ A,
                                                const f16* __restrict__ Bt,
                                                f16* __restrict__ C, int M)
{
    __shared__ f16 As[128 * 32];
    __shared__ f16 Bs[64 * 32];
    int tid = threadIdx.x;
    int row0 = blockIdx.y * 128;
    int col0 = blockIdx.x * 64;
    int w = tid >> 6, l = tid & 63;
    int wr = (w >> 1) * 64;
    int wc = (w & 1) * 32;
    int lrow = l & 15;
    int lk = (l >> 4) * 8;

    int arow = w * 32 + (l >> 2);
    int brow = w * 16 + (l >> 2);
    int seg  = (l & 3) * 8;

    f32x4 acc[4][2];
#pragma unroll
    for (int m = 0; m < 4; ++m)
#pragma unroll
        for (int n = 0; n < 2; ++n)
            acc[m][n] = (f32x4){0.f, 0.f, 0.f, 0.f};

    for (int k0 = 0; k0 < FF; k0 += 32) {
        __syncthreads();
        GLD_LDS(&A[(size_t)(row0 + arow) * FF + k0 + seg],       &As[w * 1024]);
        GLD_LDS(&A[(size_t)(row0 + arow + 16) * FF + k0 + seg],  &As[w * 1024 + 512]);
        GLD_LDS(&Bt[(size_t)(col0 + brow) * FF + k0 + seg],      &Bs[w * 512]);
        __syncthreads();
        f16x8 af[4], bf[2];
#pragma unroll
        for (int m = 0; m < 4; ++m)
            af[m] = *(const f16x8*)&As[(wr + m * 16 + lrow) * 32 + lk];
#pragma unroll
        for (int n = 0; n < 2; ++n)
            bf[n] = *(const f16x8*)&Bs[(wc + n * 16 + lrow) * 32 + lk];
#pragma unroll
        for (int m = 0; m < 4; ++m)
#pragma unroll
            for (int n = 0; n < 2; ++n)
                acc[m][n] = __builtin_amdgcn_mfma_f32_16x16x32_f16(af[m], bf[n], acc[m][n], 0, 0, 0);
    }
    int orow = (l >> 4) * 4;
#pragma unroll
    for (int m = 0; m < 4; ++m) {
#pragma unroll
        for (int r = 0; r < 4; ++r) {
            int rr = row0 + wr + m * 16 + orow + r;
            if (rr < M) {
#pragma unroll
                for (int n = 0; n < 2; ++n)
                    C[(size_t)rr * FF + col0 + wc + n * 16 + lrow] = (f16)acc[m][n][r];
            }
        }
    }
}

// ---------------- GCN aggregate (LDS-preloaded indices, f16x8 lanes) --------
// 128 threads; lanes 0..79 gather 8 cols each (16B loads)
__global__ __launch_bounds__(128) void k_agg(const f16* __restrict__ hsrc,
                      const int* __restrict__ rowptr, const int* __restrict__ colsrc,
                      const float* __restrict__ enorm, const float* __restrict__ dis,
                      const float* __restrict__ bias, f16* __restrict__ hout)
{
    __shared__ int   s_idx[128];
    __shared__ float s_w[128];
    int d = blockIdx.x;
    int lane = threadIdx.x;
    int c0 = lane * 8;
    bool act = lane < 80;
    float v[8] = {0.f, 0.f, 0.f, 0.f, 0.f, 0.f, 0.f, 0.f};
    if (act) {
        float selfw = dis[d] * dis[d];
        f16x8 self = *(const f16x8*)&hsrc[(size_t)d * FF + c0];
#pragma unroll
        for (int j = 0; j < 8; ++j) v[j] = selfw * (float)self[j];
    }
    int beg = rowptr[d], end = rowptr[d + 1];
    for (int base = beg; base < end; base += 128) {
        int cnt = (end - base < 128) ? (end - base) : 128;
        __syncthreads();
        if (lane < cnt) {
            s_idx[lane] = colsrc[base + lane];
            s_w[lane]   = enorm[base + lane];
        }
        __syncthreads();
        if (act) {
            for (int i = 0; i < cnt; ++i) {
                f16x8 p = *(const f16x8*)&hsrc[(size_t)s_idx[i] * FF + c0];
                float w = s_w[i];
#pragma unroll
                for (int j = 0; j < 8; ++j) v[j] += w * (float)p[j];
            }
        }
    }
    if (act) {
        f16x8 o;
#pragma unroll
        for (int j = 0; j < 8; ++j) {
            int c = c0 + j;
            o[j] = (f16)fmaxf(v[j] + bias[(c & 63) * 10 + (c >> 6)], 0.f);
        }
        *(f16x8*)&hout[(size_t)d * FF + c0] = o;
    }
}

// ---------------- GReTo mix as MFMA GEMM (f16 out) --------------------------
__global__ __launch_bounds__(256) void k_greto2(const f16* __restrict__ h1,
                        const f16* __restrict__ h2, const f16* __restrict__ h3,
                        const f16* __restrict__ hneg, const float* __restrict__ psi,
                        const f16* __restrict__ gWt, const float* __restrict__ gb,
                        f16* __restrict__ out)
{
    __shared__ f16 As[128][132];
    __shared__ f16 Bs[64][132];
    int tid = threadIdx.x;
    int row0 = blockIdx.x * 128;

    for (int cb = tid; cb < 1024; cb += 256) {
        int d = cb >> 4, seg = (cb & 15) * 8;
        *(f16x8*)&Bs[d][seg] = *(const f16x8*)&gWt[d * 128 + seg];
    }
    int lr = tid >> 1, side = tid & 1;
    int r = row0 + lr;
    if (r < NR) {
        int n = r / 10, t = r - (r / 10) * 10;
        size_t base = (size_t)n * FF + t * 64;
        if (side == 0) {
            float p0 = psi[n * 3], p1 = psi[n * 3 + 1], p2 = psi[n * 3 + 2];
#pragma unroll
            for (int i = 0; i < 8; ++i) {
                f16x8 a = *(const f16x8*)&h1[base + i * 8];
                f16x8 b = *(const f16x8*)&h2[base + i * 8];
                f16x8 c = *(const f16x8*)&h3[base + i * 8];
                f16x8 o;
#pragma unroll
                for (int j = 0; j < 8; ++j)
                    o[j] = (f16)(p0 * (float)a[j] + p1 * (float)b[j] + p2 * (float)c[j]);
                *(f16x8*)&As[lr][i * 8] = o;
            }
        } else {
#pragma unroll
            for (int i = 0; i < 8; ++i)
                *(f16x8*)&As[lr][64 + i * 8] = *(const f16x8*)&hneg[base + i * 8];
        }
    } else {
        f16x8 z = {};
#pragma unroll
        for (int i = 0; i < 8; ++i)
            *(f16x8*)&As[lr][side * 64 + i * 8] = z;
    }
    __syncthreads();

    int w = tid >> 6, l = tid & 63;
    int wr = w * 32;
    int lrow = l & 15;
    int lk = (l >> 4) * 8;
    f32x4 acc[2][4];
#pragma unroll
    for (int m = 0; m < 2; ++m)
#pragma unroll
        for (int n = 0; n < 4; ++n)
            acc[m][n] = (f32x4){0.f, 0.f, 0.f, 0.f};
#pragma unroll
    for (int ks = 0; ks < 4; ++ks) {
        f16x8 af[2], bf[4];
#pragma unroll
        for (int m = 0; m < 2; ++m)
            af[m] = *(const f16x8*)&As[wr + m * 16 + lrow][ks * 32 + lk];
#pragma unroll
        for (int n = 0; n < 4; ++n)
            bf[n] = *(const f16x8*)&Bs[n * 16 + lrow][ks * 32 + lk];
#pragma unroll
        for (int m = 0; m < 2; ++m)
#pragma unroll
            for (int n = 0; n < 4; ++n)
                acc[m][n] = __builtin_amdgcn_mfma_f32_16x16x32_f16(af[m], bf[n], acc[m][n], 0, 0, 0);
    }
    int orow = (l >> 4) * 4;
#pragma unroll
    for (int m = 0; m < 2; ++m) {
#pragma unroll
        for (int rr = 0; rr < 4; ++rr) {
            int ro = row0 + wr + m * 16 + orow + rr;
            if (ro < NR) {
#pragma unroll
                for (int n = 0; n < 4; ++n) {
                    int col = n * 16 + lrow;
                    out[(size_t)ro * 64 + col] = (f16)fmaxf(acc[m][n][rr] + gb[col], 0.f);
                }
            }
        }
    }
}

extern "C" void kernel_launch(void* const* d_in, const int* in_sizes, int n_in,
                              void* d_out, int out_size, void* d_ws, size_t ws_size,
                              hipStream_t stream)
{
    const float* x     = (const float*)d_in[0];
    const int*   ei    = (const int*)  d_in[1];
    const float* ea    = (const float*)d_in[2];
    const float* ndt   = (const float*)d_in[3];
    const float* tc1w1 = (const float*)d_in[4];
    const float* tc1b1 = (const float*)d_in[5];
    const float* tc1w2 = (const float*)d_in[6];
    const float* tc1b2 = (const float*)d_in[7];
    const float* Wpos  = (const float*)d_in[8];
    const float* bpos  = (const float*)d_in[9];
    const float* Wneg  = (const float*)d_in[10];
    const float* bneg  = (const float*)d_in[11];
    const float* greW  = (const float*)d_in[12];
    const float* greb  = (const float*)d_in[13];
    const float* psiW1 = (const float*)d_in[14];
    const float* psib1 = (const float*)d_in[15];
    const float* psiW2 = (const float*)d_in[16];
    const float* psib2 = (const float*)d_in[17];
    const float* tc2w1 = (const float*)d_in[18];
    const float* tc2b1 = (const float*)d_in[19];
    const float* tc2w2 = (const float*)d_in[20];
    const float* tc2b2 = (const float*)d_in[21];
    float* out = (float*)d_out;

    char* p = (char*)d_ws;
    int*   cnt   = (int*)p;   p += (size_t)NN * 4;
    int*   cursor= (int*)p;   p += (size_t)NN * 4;
    float* degp  = (float*)p; p += (size_t)NN * 4;
    float* degn  = (float*)p; p += (size_t)NN * 4;
    f16*   xT    = (f16*)p;   p += (size_t)NN * CCH * TIN * 2;
    f16*   out0h = (f16*)p;   p += (size_t)NN * FF * 2;
    f16*   h1    = (f16*)p;   p += (size_t)NN * FF * 2;
    f16*   h2    = (f16*)p;   p += (size_t)NN * FF * 2;
    f16*   h3    = (f16*)p;   p += (size_t)NN * FF * 2;
    f16*   hneg  = (f16*)p;   p += (size_t)NN * FF * 2;
    f16*   Cb16  = (f16*)p;   p += (size_t)NN * FF * 2;
    f16*   Gbuf  = (f16*)p;   p += (size_t)NN * FF * 2;
    f16*   Wtp   = (f16*)p;   p += (size_t)FF * FF * 2;
    f16*   Wtn   = (f16*)p;   p += (size_t)FF * FF * 2;
    f16*   Wtmp  = (f16*)p;   p += (size_t)2 * FF * FF * 2;
    f16*   gWt   = (f16*)p;   p += (size_t)128 * 64 * 2;
    f16*   Bw1   = (f16*)p;   p += (size_t)128 * 192 * 2;
    f16*   Bw2   = (f16*)p;   p += (size_t)128 * 192 * 2;
    float* psib  = (float*)p; p += (size_t)NN * 3 * 4;
    float* disp  = (float*)p; p += (size_t)NN * 4;
    float* disn  = (float*)p; p += (size_t)NN * 4;
    float* normp = (float*)p; p += (size_t)NE * 4;
    float* normn = (float*)p; p += (size_t)NE * 4;
    int* rowptr  = (int*)p;   p += (size_t)(NN + 1) * 4;
    int* colsrc  = (int*)p;   p += (size_t)NE * 4;

    (void)hipMemsetAsync(cnt, 0, (size_t)4 * NN * 4, stream);   // cnt+cursor+degp+degn

    k_prep<<<PB_WS, 256, 0, stream>>>(x, xT, tc1w1, tc1w2, tc2w1, tc2w2, Bw1, Bw2,
                                      ndt, psiW1, psib1, psiW2, psib2, psib,
                                      greW, gWt, ei, ea, cnt, degp, degn,
                                      Wpos, Wneg, Wtmp);
    k_scan<<<1, 1024, 0, stream>>>(cnt, rowptr, degp, degn, disp, disn);
    k_fill<<<(NE + 255) / 256, 256, 0, stream>>>(ei, ea, rowptr, cursor, disp, disn,
                                                 colsrc, normp, normn);
    dim3 pgrid(FF, 1, 2);
    k_perm2<<<pgrid, 640, 0, stream>>>(Wtmp, Wtp, Wtn);
    k_tcn1g<<<(NR + 127) / 128, 256, 0, stream>>>(xT, Bw1, tc1b1, tc1b2, out0h);

    dim3 ggrid(FF / 64, (NN + 127) / 128);
    // positive hops
    k_gemm16<<<ggrid, 256, 0, stream>>>(out0h, Wtp, Cb16, NN);
    k_agg<<<NN, 128, 0, stream>>>(Cb16, rowptr, colsrc, normp, disp, bpos, h1);
    k_gemm16<<<ggrid, 256, 0, stream>>>(h1, Wtp, Cb16, NN);
    k_agg<<<NN, 128, 0, stream>>>(Cb16, rowptr, colsrc, normp, disp, bpos, h2);
    k_gemm16<<<ggrid, 256, 0, stream>>>(h2, Wtp, Cb16, NN);
    k_agg<<<NN, 128, 0, stream>>>(Cb16, rowptr, colsrc, normp, disp, bpos, h3);
    // negative branch
    k_gemm16<<<ggrid, 256, 0, stream>>>(out0h, Wtn, Cb16, NN);
    k_agg<<<NN, 128, 0, stream>>>(Cb16, rowptr, colsrc, normn, disn, bneg, hneg);
    // GReTo channel mix (MFMA) + psi accumulation + relu -> f16
    k_greto2<<<(NR + 127) / 128, 256, 0, stream>>>(h1, h2, h3, hneg, psib, gWt, greb, Gbuf);
    // final gated TCN as direct GEMM
    k_tcn2g<<<(NR2 + 127) / 128, 256, 0, stream>>>(Gbuf, Bw2, tc2b1, tc2b2, out);
}

// Round 18
// 341.198 us; speedup vs baseline: 1.2791x; 1.0152x over previous
//
#include <hip/hip_runtime.h>
#include <math.h>

#define NN   10000   // nodes
#define NE   160000  // edges
#define CCH  64      // in/out channels
#define TIN  12      // input time steps
#define HCH  64      // hidden channels
#define TSP  10      // T - 2
#define FF   640     // H * TSP
#define TOUT 8       // TSP - 2
#define NR   (NN * TSP)    // 100000 rows
#define NR2  (NN * TOUT)   // 80000 rows

typedef _Float16 f16;
typedef _Float16 f16x8 __attribute__((ext_vector_type(8)));
typedef float f32x4 __attribute__((ext_vector_type(4)));

#define GLD_LDS(gsrc, ldst) __builtin_amdgcn_global_load_lds( \
    (const __attribute__((address_space(1))) void*)(gsrc),    \
    (__attribute__((address_space(3))) void*)(ldst), 16, 0, 0)

// ---------------- mega prep: xT | wconv | psi | gwt | deg | wsplit ----------
#define PB_XT   2500
#define PB_WC   (PB_XT + 192)
#define PB_PSI  (PB_WC + 40)
#define PB_GWT  (PB_PSI + 32)
#define PB_DEG  (PB_GWT + 625)
#define PB_WS   (PB_DEG + 800)

__global__ __launch_bounds__(256) void k_prep(
    const float* __restrict__ x, f16* __restrict__ xT,
    const float* __restrict__ tc1w1, const float* __restrict__ tc1w2,
    const float* __restrict__ tc2w1, const float* __restrict__ tc2w2,
    f16* __restrict__ Bw1, f16* __restrict__ Bw2,
    const float* __restrict__ ND, const float* __restrict__ pW1,
    const float* __restrict__ pb1, const float* __restrict__ pW2,
    const float* __restrict__ pb2, float* __restrict__ psi,
    const float* __restrict__ gW, f16* __restrict__ gWt,
    const int* __restrict__ ei, const float* __restrict__ ea,
    int* __restrict__ cnt, float* __restrict__ degp, float* __restrict__ degn,
    const float* __restrict__ Wpos, const float* __restrict__ Wneg,
    f16* __restrict__ Wtmp)
{
    __shared__ float smem[4 * 832];   // xT: 4 nodes, padded row stride 13 per c
    int blk = blockIdx.x;
    int tid = threadIdx.x;

    if (blk < PB_XT) {                       // ---- x transpose (pad 12->13) ----
        int node0 = blk * 4;
        for (int i = tid; i < 4 * CCH * TIN; i += 256) {
            int nn = i / (CCH * TIN), off = i % (CCH * TIN);
            int g = node0 + nn;
            int c = off / 12, t = off - c * 12;
            smem[nn * 832 + c * 13 + t] = (g < NN) ? x[(size_t)g * CCH * TIN + off] : 0.f;
        }
        __syncthreads();
        for (int i = tid; i < 4 * CCH * TIN; i += 256) {
            int nn = i / (CCH * TIN), off = i % (CCH * TIN);
            int t = off >> 6, c = off & 63;
            int g = node0 + nn;
            if (g < NN) xT[(size_t)g * (CCH * TIN) + off] = (f16)smem[nn * 832 + c * 13 + t];
        }
    } else if (blk < PB_WC) {                // ---- conv weights ----
        int t2 = (blk - PB_XT) * 256 + tid;
        const int half = 128 * 192;
        if (t2 < 2 * half) {
            int which = t2 / half, r = t2 % half;
            const float* s1 = which ? tc2w1 : tc1w1;
            const float* s2 = which ? tc2w2 : tc1w2;
            f16* dst = which ? Bw2 : Bw1;
            int o = r / 192, j = r % 192;
            int k = j >> 6, ci = j & 63;
            const float* src = (o < 64) ? s1 : s2;
            dst[r] = (f16)src[((o & 63) * 64 + ci) * 3 + k];
        }
    } else if (blk < PB_PSI) {               // ---- psi MLP ----
        int n = (blk - PB_WC) * 256 + tid;
        if (n < NN) {
            float d0 = ND[n * 3], d1 = ND[n * 3 + 1], d2 = ND[n * 3 + 2];
            float o0 = pb2[0], o1 = pb2[1], o2 = pb2[2];
            for (int j = 0; j < 64; ++j) {
                float hv = d0 * pW1[j] + d1 * pW1[64 + j] + d2 * pW1[128 + j] + pb1[j];
                hv = fmaxf(hv, 0.f);
                o0 += hv * pW2[j * 3 + 0];
                o1 += hv * pW2[j * 3 + 1];
                o2 += hv * pW2[j * 3 + 2];
            }
            psi[n * 3 + 0] = o0; psi[n * 3 + 1] = o1; psi[n * 3 + 2] = o2;
        }
    } else if (blk < PB_GWT) {               // ---- gW transpose ----
        int t2 = (blk - PB_PSI) * 256 + tid;
        if (t2 < 128 * 64) {
            int c = t2 >> 6, d = t2 & 63;
            gWt[d * 128 + c] = (f16)gW[t2];
        }
    } else if (blk < PB_DEG) {               // ---- degree ----
        int e = (blk - PB_GWT) * 256 + tid;
        if (e < NE) {
            int d = ei[NE + e];
            atomicAdd(&cnt[d], 1);
            atomicAdd(&degp[d], ea[e * 2 + 0] + 1.f);
            atomicAdd(&degn[d], ea[e * 2 + 1] + 1.f);
        }
    } else {                                 // ---- W transpose+cast ----
        float (*tt)[33] = (float(*)[33])smem;
        int rel = blk - PB_DEG;
        int z = rel / 400, r2 = rel % 400;
        const float* W = z ? Wneg : Wpos;
        f16* dst = Wtmp + (size_t)z * FF * FF;
        int bx = (r2 / 20) * 32;
        int by = (r2 % 20) * 32;
        int tx = tid & 31, ty = tid >> 5;
#pragma unroll
        for (int j = 0; j < 4; ++j)
            tt[ty + j * 8][tx] = W[(size_t)(bx + ty + j * 8) * 640 + by + tx];
        __syncthreads();
#pragma unroll
        for (int j = 0; j < 4; ++j)
            dst[(size_t)(by + ty + j * 8) * 640 + bx + tx] = (f16)tt[tx][ty + j * 8];
    }
}

// ---------------- TCN1 as direct GEMM, B staged in LDS ----------------------
__global__ __launch_bounds__(256) void k_tcn1g(const f16* __restrict__ A,
                                               const f16* __restrict__ Bw,
                                               const float* __restrict__ b1,
                                               const float* __restrict__ b2,
                                               f16* __restrict__ out)
{
    __shared__ f16 Bs[128][200];
    int tid = threadIdx.x;
#pragma unroll
    for (int i = 0; i < 12; ++i) {
        int c = tid + i * 256;
        int row = c / 24, seg = (c % 24) * 8;
        *(f16x8*)&Bs[row][seg] = *(const f16x8*)&Bw[row * 192 + seg];
    }
    __syncthreads();

    int w = tid >> 6, l = tid & 63;
    int row0 = blockIdx.x * 128 + w * 32;
    int lrow = l & 15, lk = (l >> 4) * 8;

    size_t abase[2];
#pragma unroll
    for (int m = 0; m < 2; ++m) {
        int rr = row0 + m * 16 + lrow;
        int rc = (rr < NR) ? rr : NR - 1;
        int n = rc / 10, t = rc - n * 10;
        abase[m] = (size_t)n * 768 + t * 64 + lk;
    }
    f32x4 acc[2][8];
#pragma unroll
    for (int m = 0; m < 2; ++m)
#pragma unroll
        for (int n = 0; n < 8; ++n)
            acc[m][n] = (f32x4){0.f, 0.f, 0.f, 0.f};

#pragma unroll
    for (int ks = 0; ks < 6; ++ks) {
        f16x8 af[2], bf[8];
#pragma unroll
        for (int m = 0; m < 2; ++m)
            af[m] = *(const f16x8*)&A[abase[m] + ks * 32];
#pragma unroll
        for (int n = 0; n < 8; ++n)
            bf[n] = *(const f16x8*)&Bs[n * 16 + lrow][ks * 32 + lk];
#pragma unroll
        for (int m = 0; m < 2; ++m)
#pragma unroll
            for (int n = 0; n < 8; ++n)
                acc[m][n] = __builtin_amdgcn_mfma_f32_16x16x32_f16(af[m], bf[n], acc[m][n], 0, 0, 0);
    }
    int og = (l >> 4) * 4;
#pragma unroll
    for (int m = 0; m < 2; ++m) {
#pragma unroll
        for (int n = 0; n < 4; ++n) {
            int h = n * 16 + lrow;
            float bb1 = b1[h], bb2 = b2[h];
#pragma unroll
            for (int rr = 0; rr < 4; ++rr) {
                int R = row0 + m * 16 + og + rr;
                if (R < NR) {
                    float g1 = acc[m][n][rr] + bb1;
                    float g2 = acc[m][n + 4][rr] + bb2;
                    float e = __expf(2.f * g1);
                    float th = 1.f - 2.f / (e + 1.f);
                    float sg = 1.f / (1.f + __expf(-g2));
                    out[(size_t)R * 64 + h] = (f16)(th * sg);
                }
            }
        }
    }
}

// TCN2
__global__ __launch_bounds__(256) void k_tcn2g(const f16* __restrict__ A,
                                               const f16* __restrict__ Bw,
                                               const float* __restrict__ b1,
                                               const float* __restrict__ b2,
                                               float* __restrict__ out)
{
    __shared__ f16 Bs[128][200];
    int tid = threadIdx.x;
#pragma unroll
    for (int i = 0; i < 12; ++i) {
        int c = tid + i * 256;
        int row = c / 24, seg = (c % 24) * 8;
        *(f16x8*)&Bs[row][seg] = *(const f16x8*)&Bw[row * 192 + seg];
    }
    __syncthreads();

    int w = tid >> 6, l = tid & 63;
    int row0 = blockIdx.x * 128 + w * 32;
    int lrow = l & 15, lk = (l >> 4) * 8;

    size_t abase[2];
#pragma unroll
    for (int m = 0; m < 2; ++m) {
        int rr = row0 + m * 16 + lrow;
        int rc = (rr < NR2) ? rr : NR2 - 1;
        int n = rc >> 3, t = rc & 7;
        abase[m] = (size_t)n * FF + t * 64 + lk;
    }
    f32x4 acc[2][8];
#pragma unroll
    for (int m = 0; m < 2; ++m)
#pragma unroll
        for (int n = 0; n < 8; ++n)
            acc[m][n] = (f32x4){0.f, 0.f, 0.f, 0.f};

#pragma unroll
    for (int ks = 0; ks < 6; ++ks) {
        f16x8 af[2], bf[8];
#pragma unroll
        for (int m = 0; m < 2; ++m)
            af[m] = *(const f16x8*)&A[abase[m] + ks * 32];
#pragma unroll
        for (int n = 0; n < 8; ++n)
            bf[n] = *(const f16x8*)&Bs[n * 16 + lrow][ks * 32 + lk];
#pragma unroll
        for (int m = 0; m < 2; ++m)
#pragma unroll
            for (int n = 0; n < 8; ++n)
                acc[m][n] = __builtin_amdgcn_mfma_f32_16x16x32_f16(af[m], bf[n], acc[m][n], 0, 0, 0);
    }
    int og = (l >> 4) * 4;
#pragma unroll
    for (int m = 0; m < 2; ++m) {
#pragma unroll
        for (int n = 0; n < 4; ++n) {
            int c = n * 16 + lrow;
            float bb1 = b1[c], bb2 = b2[c];
#pragma unroll
            for (int rr = 0; rr < 4; ++rr) {
                int R = row0 + m * 16 + og + rr;
                if (R < NR2) {
                    float g1 = acc[m][n][rr] + bb1;
                    float g2 = acc[m][n + 4][rr] + bb2;
                    float e = __expf(2.f * g1);
                    float th = 1.f - 2.f / (e + 1.f);
                    float sg = 1.f / (1.f + __expf(-g2));
                    int n2 = R >> 3, t2 = R & 7;
                    out[(size_t)n2 * (CCH * TOUT) + c * TOUT + t2] = th * sg;
                }
            }
        }
    }
}

// ---------------- scan (thread-coarsened) + dis fold ------------------------
__global__ __launch_bounds__(1024) void k_scan(const int* __restrict__ cnt,
                      int* __restrict__ rowptr,
                      const float* __restrict__ degp, const float* __restrict__ degn,
                      float* __restrict__ disp, float* __restrict__ disn)
{
    int tid = threadIdx.x;
    for (int i = tid; i < NN; i += 1024) {
        disp[i] = 1.f / sqrtf(degp[i] + 1.f);
        disn[i] = 1.f / sqrtf(degn[i] + 1.f);
    }
    __shared__ int part[1024];
    int base = tid * 10;
    int loc[10];
    int sum = 0;
    if (tid < 1000) {
#pragma unroll
        for (int j = 0; j < 10; ++j) { loc[j] = sum; sum += cnt[base + j]; }
    }
    part[tid] = (tid < 1000) ? sum : 0;
    __syncthreads();
    for (int off = 1; off < 1024; off <<= 1) {
        int t = (tid >= off) ? part[tid - off] : 0;
        __syncthreads();
        part[tid] += t;
        __syncthreads();
    }
    int prefix = (tid > 0) ? part[tid - 1] : 0;
    if (tid < 1000) {
#pragma unroll
        for (int j = 0; j < 10; ++j) rowptr[base + j] = prefix + loc[j];
    }
    if (tid == 0) rowptr[NN] = part[1023];
}

// ---------------- CSR fill ---------------------------------------------------
__global__ void k_fill(const int* __restrict__ ei, const float* __restrict__ ea,
                       const int* __restrict__ rowptr, int* __restrict__ cursor,
                       const float* __restrict__ disp, const float* __restrict__ disn,
                       int* __restrict__ colsrc, float* __restrict__ normp, float* __restrict__ normn)
{
    int e = blockIdx.x * blockDim.x + threadIdx.x;
    if (e >= NE) return;
    int s = ei[e], d = ei[NE + e];
    int slot = atomicAdd(&cursor[d], 1);
    int idx = rowptr[d] + slot;
    colsrc[idx] = s;
    normp[idx] = disp[s] * (ea[e * 2 + 0] + 1.f) * disp[d];
    normn[idx] = disn[s] * (ea[e * 2 + 1] + 1.f) * disn[d];
}

// ---------------- permute rows+cols to f' order (batched via z) -------------
__global__ __launch_bounds__(640) void k_perm2(const f16* __restrict__ Wt0,
                                               f16* __restrict__ Wp, f16* __restrict__ Wn)
{
    __shared__ f16 row[FF];
    const f16* src = Wt0 + (size_t)blockIdx.z * FF * FF;
    f16* dst = blockIdx.z ? Wn : Wp;
    int np = blockIdx.x;
    int n = (np & 63) * 10 + (np >> 6);
    int tid = threadIdx.x;
    row[tid] = src[(size_t)n * FF + tid];
    __syncthreads();
    int k = (tid & 63) * 10 + (tid >> 6);
    dst[(size_t)np * FF + tid] = row[k];
}

// ---------------- f16 MFMA GEMM, double-buffered global_load_lds ------------
__global__ __launch_bounds__(256) void k_gemm16(const f16* __restrict__ A,
                                                const f16* __restrict__ Bt,
                                                f16* __restrict__ C, int M)
{
    __shared__ f16 As[2][128 * 32];
    __shared__ f16 Bs[2][64 * 32];
    int tid = threadIdx.x;
    int row0 = blockIdx.y * 128;
    int col0 = blockIdx.x * 64;
    int w = tid >> 6, l = tid & 63;
    int wr = (w >> 1) * 64;
    int wc = (w & 1) * 32;
    int lrow = l & 15;
    int lk = (l >> 4) * 8;

    int arow = w * 32 + (l >> 2);
    int brow = w * 16 + (l >> 2);
    int seg  = (l & 3) * 8;

    f32x4 acc[4][2];
#pragma unroll
    for (int m = 0; m < 4; ++m)
#pragma unroll
        for (int n = 0; n < 2; ++n)
            acc[m][n] = (f32x4){0.f, 0.f, 0.f, 0.f};

    // prologue: stage k0=0 into buf 0
    GLD_LDS(&A[(size_t)(row0 + arow) * FF + seg],       &As[0][w * 1024]);
    GLD_LDS(&A[(size_t)(row0 + arow + 16) * FF + seg],  &As[0][w * 1024 + 512]);
    GLD_LDS(&Bt[(size_t)(col0 + brow) * FF + seg],      &Bs[0][w * 512]);
    __syncthreads();

    int cur = 0;
    for (int step = 0; step < 20; ++step) {
        if (step < 19) {
            int k1 = (step + 1) * 32;
            GLD_LDS(&A[(size_t)(row0 + arow) * FF + k1 + seg],       &As[cur ^ 1][w * 1024]);
            GLD_LDS(&A[(size_t)(row0 + arow + 16) * FF + k1 + seg],  &As[cur ^ 1][w * 1024 + 512]);
            GLD_LDS(&Bt[(size_t)(col0 + brow) * FF + k1 + seg],      &Bs[cur ^ 1][w * 512]);
        }
        f16x8 af[4], bf[2];
#pragma unroll
        for (int m = 0; m < 4; ++m)
            af[m] = *(const f16x8*)&As[cur][(wr + m * 16 + lrow) * 32 + lk];
#pragma unroll
        for (int n = 0; n < 2; ++n)
            bf[n] = *(const f16x8*)&Bs[cur][(wc + n * 16 + lrow) * 32 + lk];
#pragma unroll
        for (int m = 0; m < 4; ++m)
#pragma unroll
            for (int n = 0; n < 2; ++n)
                acc[m][n] = __builtin_amdgcn_mfma_f32_16x16x32_f16(af[m], bf[n], acc[m][n], 0, 0, 0);
        __syncthreads();   // drains vmcnt: next buf ready; all reads of cur done
        cur ^= 1;
    }
    int orow = (l >> 4) * 4;
#pragma unroll
    for (int m = 0; m < 4; ++m) {
#pragma unroll
        for (int r = 0; r < 4; ++r) {
            int rr = row0 + wr + m * 16 + orow + r;
            if (rr < M) {
#pragma unroll
                for (int n = 0; n < 2; ++n)
                    C[(size_t)rr * FF + col0 + wc + n * 16 + lrow] = (f16)acc[m][n][r];
            }
        }
    }
}

// ---------------- GCN aggregate (LDS-preloaded indices, f16x8 lanes) --------
__global__ __launch_bounds__(128) void k_agg(const f16* __restrict__ hsrc,
                      const int* __restrict__ rowptr, const int* __restrict__ colsrc,
                      const float* __restrict__ enorm, const float* __restrict__ dis,
                      const float* __restrict__ bias, f16* __restrict__ hout)
{
    __shared__ int   s_idx[128];
    __shared__ float s_w[128];
    int d = blockIdx.x;
    int lane = threadIdx.x;
    int c0 = lane * 8;
    bool act = lane < 80;
    float v[8] = {0.f, 0.f, 0.f, 0.f, 0.f, 0.f, 0.f, 0.f};
    if (act) {
        float selfw = dis[d] * dis[d];
        f16x8 self = *(const f16x8*)&hsrc[(size_t)d * FF + c0];
#pragma unroll
        for (int j = 0; j < 8; ++j) v[j] = selfw * (float)self[j];
    }
    int beg = rowptr[d], end = rowptr[d + 1];
    for (int base = beg; base < end; base += 128) {
        int cnt = (end - base < 128) ? (end - base) : 128;
        __syncthreads();
        if (lane < cnt) {
            s_idx[lane] = colsrc[base + lane];
            s_w[lane]   = enorm[base + lane];
        }
        __syncthreads();
        if (act) {
            for (int i = 0; i < cnt; ++i) {
                f16x8 p = *(const f16x8*)&hsrc[(size_t)s_idx[i] * FF + c0];
                float w = s_w[i];
#pragma unroll
                for (int j = 0; j < 8; ++j) v[j] += w * (float)p[j];
            }
        }
    }
    if (act) {
        f16x8 o;
#pragma unroll
        for (int j = 0; j < 8; ++j) {
            int c = c0 + j;
            o[j] = (f16)fmaxf(v[j] + bias[(c & 63) * 10 + (c >> 6)], 0.f);
        }
        *(f16x8*)&hout[(size_t)d * FF + c0] = o;
    }
}

// ---------------- GReTo mix as MFMA GEMM (f16 out) --------------------------
__global__ __launch_bounds__(256) void k_greto2(const f16* __restrict__ h1,
                        const f16* __restrict__ h2, const f16* __restrict__ h3,
                        const f16* __restrict__ hneg, const float* __restrict__ psi,
                        const f16* __restrict__ gWt, const float* __restrict__ gb,
                        f16* __restrict__ out)
{
    __shared__ f16 As[128][132];
    __shared__ f16 Bs[64][132];
    int tid = threadIdx.x;
    int row0 = blockIdx.x * 128;

    for (int cb = tid; cb < 1024; cb += 256) {
        int d = cb >> 4, seg = (cb & 15) * 8;
        *(f16x8*)&Bs[d][seg] = *(const f16x8*)&gWt[d * 128 + seg];
    }
    int lr = tid >> 1, side = tid & 1;
    int r = row0 + lr;
    if (r < NR) {
        int n = r / 10, t = r - (r / 10) * 10;
        size_t base = (size_t)n * FF + t * 64;
        if (side == 0) {
            float p0 = psi[n * 3], p1 = psi[n * 3 + 1], p2 = psi[n * 3 + 2];
#pragma unroll
            for (int i = 0; i < 8; ++i) {
                f16x8 a = *(const f16x8*)&h1[base + i * 8];
                f16x8 b = *(const f16x8*)&h2[base + i * 8];
                f16x8 c = *(const f16x8*)&h3[base + i * 8];
                f16x8 o;
#pragma unroll
                for (int j = 0; j < 8; ++j)
                    o[j] = (f16)(p0 * (float)a[j] + p1 * (float)b[j] + p2 * (float)c[j]);
                *(f16x8*)&As[lr][i * 8] = o;
            }
        } else {
#pragma unroll
            for (int i = 0; i < 8; ++i)
                *(f16x8*)&As[lr][64 + i * 8] = *(const f16x8*)&hneg[base + i * 8];
        }
    } else {
        f16x8 z = {};
#pragma unroll
        for (int i = 0; i < 8; ++i)
            *(f16x8*)&As[lr][side * 64 + i * 8] = z;
    }
    __syncthreads();

    int w = tid >> 6, l = tid & 63;
    int wr = w * 32;
    int lrow = l & 15;
    int lk = (l >> 4) * 8;
    f32x4 acc[2][4];
#pragma unroll
    for (int m = 0; m < 2; ++m)
#pragma unroll
        for (int n = 0; n < 4; ++n)
            acc[m][n] = (f32x4){0.f, 0.f, 0.f, 0.f};
#pragma unroll
    for (int ks = 0; ks < 4; ++ks) {
        f16x8 af[2], bf[4];
#pragma unroll
        for (int m = 0; m < 2; ++m)
            af[m] = *(const f16x8*)&As[wr + m * 16 + lrow][ks * 32 + lk];
#pragma unroll
        for (int n = 0; n < 4; ++n)
            bf[n] = *(const f16x8*)&Bs[n * 16 + lrow][ks * 32 + lk];
#pragma unroll
        for (int m = 0; m < 2; ++m)
#pragma unroll
            for (int n = 0; n < 4; ++n)
                acc[m][n] = __builtin_amdgcn_mfma_f32_16x16x32_f16(af[m], bf[n], acc[m][n], 0, 0, 0);
    }
    int orow = (l >> 4) * 4;
#pragma unroll
    for (int m = 0; m < 2; ++m) {
#pragma unroll
        for (int rr = 0; rr < 4; ++rr) {
            int ro = row0 + wr + m * 16 + orow + rr;
            if (ro < NR) {
#pragma unroll
                for (int n = 0; n < 4; ++n) {
                    int col = n * 16 + lrow;
                    out[(size_t)ro * 64 + col] = (f16)fmaxf(acc[m][n][rr] + gb[col], 0.f);
                }
            }
        }
    }
}

extern "C" void kernel_launch(void* const* d_in, const int* in_sizes, int n_in,
                              void* d_out, int out_size, void* d_ws, size_t ws_size,
                              hipStream_t stream)
{
    const float* x     = (const float*)d_in[0];
    const int*   ei    = (const int*)  d_in[1];
    const float* ea    = (const float*)d_in[2];
    const float* ndt   = (const float*)d_in[3];
    const float* tc1w1 = (const float*)d_in[4];
    const float* tc1b1 = (const float*)d_in[5];
    const float* tc1w2 = (const float*)d_in[6];
    const float* tc1b2 = (const float*)d_in[7];
    const float* Wpos  = (const float*)d_in[8];
    const float* bpos  = (const float*)d_in[9];
    const float* Wneg  = (const float*)d_in[10];
    const float* bneg  = (const float*)d_in[11];
    const float* greW  = (const float*)d_in[12];
    const float* greb  = (const float*)d_in[13];
    const float* psiW1 = (const float*)d_in[14];
    const float* psib1 = (const float*)d_in[15];
    const float* psiW2 = (const float*)d_in[16];
    const float* psib2 = (const float*)d_in[17];
    const float* tc2w1 = (const float*)d_in[18];
    const float* tc2b1 = (const float*)d_in[19];
    const float* tc2w2 = (const float*)d_in[20];
    const float* tc2b2 = (const float*)d_in[21];
    float* out = (float*)d_out;

    char* p = (char*)d_ws;
    int*   cnt   = (int*)p;   p += (size_t)NN * 4;
    int*   cursor= (int*)p;   p += (size_t)NN * 4;
    float* degp  = (float*)p; p += (size_t)NN * 4;
    float* degn  = (float*)p; p += (size_t)NN * 4;
    f16*   xT    = (f16*)p;   p += (size_t)NN * CCH * TIN * 2;
    f16*   out0h = (f16*)p;   p += (size_t)NN * FF * 2;
    f16*   h1    = (f16*)p;   p += (size_t)NN * FF * 2;
    f16*   h2    = (f16*)p;   p += (size_t)NN * FF * 2;
    f16*   h3    = (f16*)p;   p += (size_t)NN * FF * 2;
    f16*   hneg  = (f16*)p;   p += (size_t)NN * FF * 2;
    f16*   Cb16  = (f16*)p;   p += (size_t)NN * FF * 2;
    f16*   Gbuf  = (f16*)p;   p += (size_t)NN * FF * 2;
    f16*   Wtp   = (f16*)p;   p += (size_t)FF * FF * 2;
    f16*   Wtn   = (f16*)p;   p += (size_t)FF * FF * 2;
    f16*   Wtmp  = (f16*)p;   p += (size_t)2 * FF * FF * 2;
    f16*   gWt   = (f16*)p;   p += (size_t)128 * 64 * 2;
    f16*   Bw1   = (f16*)p;   p += (size_t)128 * 192 * 2;
    f16*   Bw2   = (f16*)p;   p += (size_t)128 * 192 * 2;
    float* psib  = (float*)p; p += (size_t)NN * 3 * 4;
    float* disp  = (float*)p; p += (size_t)NN * 4;
    float* disn  = (float*)p; p += (size_t)NN * 4;
    float* normp = (float*)p; p += (size_t)NE * 4;
    float* normn = (float*)p; p += (size_t)NE * 4;
    int* rowptr  = (int*)p;   p += (size_t)(NN + 1) * 4;
    int* colsrc  = (int*)p;   p += (size_t)NE * 4;

    (void)hipMemsetAsync(cnt, 0, (size_t)4 * NN * 4, stream);   // cnt+cursor+degp+degn

    k_prep<<<PB_WS, 256, 0, stream>>>(x, xT, tc1w1, tc1w2, tc2w1, tc2w2, Bw1, Bw2,
                                      ndt, psiW1, psib1, psiW2, psib2, psib,
                                      greW, gWt, ei, ea, cnt, degp, degn,
                                      Wpos, Wneg, Wtmp);
    k_scan<<<1, 1024, 0, stream>>>(cnt, rowptr, degp, degn, disp, disn);
    k_fill<<<(NE + 255) / 256, 256, 0, stream>>>(ei, ea, rowptr, cursor, disp, disn,
                                                 colsrc, normp, normn);
    dim3 pgrid(FF, 1, 2);
    k_perm2<<<pgrid, 640, 0, stream>>>(Wtmp, Wtp, Wtn);
    k_tcn1g<<<(NR + 127) / 128, 256, 0, stream>>>(xT, Bw1, tc1b1, tc1b2, out0h);

    dim3 ggrid(FF / 64, (NN + 127) / 128);
    // positive hops
    k_gemm16<<<ggrid, 256, 0, stream>>>(out0h, Wtp, Cb16, NN);
    k_agg<<<NN, 128, 0, stream>>>(Cb16, rowptr, colsrc, normp, disp, bpos, h1);
    k_gemm16<<<ggrid, 256, 0, stream>>>(h1, Wtp, Cb16, NN);
    k_agg<<<NN, 128, 0, stream>>>(Cb16, rowptr, colsrc, normp, disp, bpos, h2);
    k_gemm16<<<ggrid, 256, 0, stream>>>(h2, Wtp, Cb16, NN);
    k_agg<<<NN, 128, 0, stream>>>(Cb16, rowptr, colsrc, normp, disp, bpos, h3);
    // negative branch
    k_gemm16<<<ggrid, 256, 0, stream>>>(out0h, Wtn, Cb16, NN);
    k_agg<<<NN, 128, 0, stream>>>(Cb16, rowptr, colsrc, normn, disn, bneg, hneg);
    // GReTo channel mix (MFMA) + psi accumulation + relu -> f16
    k_greto2<<<(NR + 127) / 128, 256, 0, stream>>>(h1, h2, h3, hneg, psib, gWt, greb, Gbuf);
    // final gated TCN as direct GEMM
    k_tcn2g<<<(NR2 + 127) / 128, 256, 0, stream>>>(Gbuf, Bw2, tc2b1, tc2b2, out);
}

// Round 19
// 334.332 us; speedup vs baseline: 1.3054x; 1.0205x over previous
//
#include <hip/hip_runtime.h>
#include <math.h>

#define NN   10000   // nodes
#define NE   160000  // edges
#define CCH  64      // in/out channels
#define TIN  12      // input time steps
#define HCH  64      // hidden channels
#define TSP  10      // T - 2
#define FF   640     // H * TSP
#define TOUT 8       // TSP - 2
#define NR   (NN * TSP)    // 100000 rows
#define NR2  (NN * TOUT)   // 80000 rows

typedef _Float16 f16;
typedef _Float16 f16x8 __attribute__((ext_vector_type(8)));
typedef float f32x4 __attribute__((ext_vector_type(4)));

#define GLD_LDS(gsrc, ldst) __builtin_amdgcn_global_load_lds( \
    (const __attribute__((address_space(1))) void*)(gsrc),    \
    (__attribute__((address_space(3))) void*)(ldst), 16, 0, 0)

// ---------------- mega prep: xT | wconv | psi | gwt | deg | wsplit ----------
#define PB_XT   2500
#define PB_WC   (PB_XT + 192)
#define PB_PSI  (PB_WC + 40)
#define PB_GWT  (PB_PSI + 32)
#define PB_DEG  (PB_GWT + 625)
#define PB_WS   (PB_DEG + 800)

__global__ __launch_bounds__(256) void k_prep(
    const float* __restrict__ x, f16* __restrict__ xT,
    const float* __restrict__ tc1w1, const float* __restrict__ tc1w2,
    const float* __restrict__ tc2w1, const float* __restrict__ tc2w2,
    f16* __restrict__ Bw1, f16* __restrict__ Bw2,
    const float* __restrict__ ND, const float* __restrict__ pW1,
    const float* __restrict__ pb1, const float* __restrict__ pW2,
    const float* __restrict__ pb2, float* __restrict__ psi,
    const float* __restrict__ gW, f16* __restrict__ gWt,
    const int* __restrict__ ei, const float* __restrict__ ea,
    int* __restrict__ cnt, float* __restrict__ degp, float* __restrict__ degn,
    const float* __restrict__ Wpos, const float* __restrict__ Wneg,
    f16* __restrict__ Wtmp)
{
    __shared__ float smem[4 * 832];
    int blk = blockIdx.x;
    int tid = threadIdx.x;

    if (blk < PB_XT) {                       // ---- x transpose (pad 12->13) ----
        int node0 = blk * 4;
        for (int i = tid; i < 4 * CCH * TIN; i += 256) {
            int nn = i / (CCH * TIN), off = i % (CCH * TIN);
            int g = node0 + nn;
            int c = off / 12, t = off - c * 12;
            smem[nn * 832 + c * 13 + t] = (g < NN) ? x[(size_t)g * CCH * TIN + off] : 0.f;
        }
        __syncthreads();
        for (int i = tid; i < 4 * CCH * TIN; i += 256) {
            int nn = i / (CCH * TIN), off = i % (CCH * TIN);
            int t = off >> 6, c = off & 63;
            int g = node0 + nn;
            if (g < NN) xT[(size_t)g * (CCH * TIN) + off] = (f16)smem[nn * 832 + c * 13 + t];
        }
    } else if (blk < PB_WC) {                // ---- conv weights ----
        int t2 = (blk - PB_XT) * 256 + tid;
        const int half = 128 * 192;
        if (t2 < 2 * half) {
            int which = t2 / half, r = t2 % half;
            const float* s1 = which ? tc2w1 : tc1w1;
            const float* s2 = which ? tc2w2 : tc1w2;
            f16* dst = which ? Bw2 : Bw1;
            int o = r / 192, j = r % 192;
            int k = j >> 6, ci = j & 63;
            const float* src = (o < 64) ? s1 : s2;
            dst[r] = (f16)src[((o & 63) * 64 + ci) * 3 + k];
        }
    } else if (blk < PB_PSI) {               // ---- psi MLP ----
        int n = (blk - PB_WC) * 256 + tid;
        if (n < NN) {
            float d0 = ND[n * 3], d1 = ND[n * 3 + 1], d2 = ND[n * 3 + 2];
            float o0 = pb2[0], o1 = pb2[1], o2 = pb2[2];
            for (int j = 0; j < 64; ++j) {
                float hv = d0 * pW1[j] + d1 * pW1[64 + j] + d2 * pW1[128 + j] + pb1[j];
                hv = fmaxf(hv, 0.f);
                o0 += hv * pW2[j * 3 + 0];
                o1 += hv * pW2[j * 3 + 1];
                o2 += hv * pW2[j * 3 + 2];
            }
            psi[n * 3 + 0] = o0; psi[n * 3 + 1] = o1; psi[n * 3 + 2] = o2;
        }
    } else if (blk < PB_GWT) {               // ---- gW transpose ----
        int t2 = (blk - PB_PSI) * 256 + tid;
        if (t2 < 128 * 64) {
            int c = t2 >> 6, d = t2 & 63;
            gWt[d * 128 + c] = (f16)gW[t2];
        }
    } else if (blk < PB_DEG) {               // ---- degree ----
        int e = (blk - PB_GWT) * 256 + tid;
        if (e < NE) {
            int d = ei[NE + e];
            atomicAdd(&cnt[d], 1);
            atomicAdd(&degp[d], ea[e * 2 + 0] + 1.f);
            atomicAdd(&degn[d], ea[e * 2 + 1] + 1.f);
        }
    } else {                                 // ---- W transpose+cast ----
        float (*tt)[33] = (float(*)[33])smem;
        int rel = blk - PB_DEG;
        int z = rel / 400, r2 = rel % 400;
        const float* W = z ? Wneg : Wpos;
        f16* dst = Wtmp + (size_t)z * FF * FF;
        int bx = (r2 / 20) * 32;
        int by = (r2 % 20) * 32;
        int tx = tid & 31, ty = tid >> 5;
#pragma unroll
        for (int j = 0; j < 4; ++j)
            tt[ty + j * 8][tx] = W[(size_t)(bx + ty + j * 8) * 640 + by + tx];
        __syncthreads();
#pragma unroll
        for (int j = 0; j < 4; ++j)
            dst[(size_t)(by + ty + j * 8) * 640 + bx + tx] = (f16)tt[tx][ty + j * 8];
    }
}

// ---------------- TCN1 as direct GEMM, B staged in LDS ----------------------
__global__ __launch_bounds__(256) void k_tcn1g(const f16* __restrict__ A,
                                               const f16* __restrict__ Bw,
                                               const float* __restrict__ b1,
                                               const float* __restrict__ b2,
                                               f16* __restrict__ out)
{
    __shared__ f16 Bs[128][200];
    int tid = threadIdx.x;
#pragma unroll
    for (int i = 0; i < 12; ++i) {
        int c = tid + i * 256;
        int row = c / 24, seg = (c % 24) * 8;
        *(f16x8*)&Bs[row][seg] = *(const f16x8*)&Bw[row * 192 + seg];
    }
    __syncthreads();

    int w = tid >> 6, l = tid & 63;
    int row0 = blockIdx.x * 128 + w * 32;
    int lrow = l & 15, lk = (l >> 4) * 8;

    size_t abase[2];
#pragma unroll
    for (int m = 0; m < 2; ++m) {
        int rr = row0 + m * 16 + lrow;
        int rc = (rr < NR) ? rr : NR - 1;
        int n = rc / 10, t = rc - n * 10;
        abase[m] = (size_t)n * 768 + t * 64 + lk;
    }
    f32x4 acc[2][8];
#pragma unroll
    for (int m = 0; m < 2; ++m)
#pragma unroll
        for (int n = 0; n < 8; ++n)
            acc[m][n] = (f32x4){0.f, 0.f, 0.f, 0.f};

#pragma unroll
    for (int ks = 0; ks < 6; ++ks) {
        f16x8 af[2], bf[8];
#pragma unroll
        for (int m = 0; m < 2; ++m)
            af[m] = *(const f16x8*)&A[abase[m] + ks * 32];
#pragma unroll
        for (int n = 0; n < 8; ++n)
            bf[n] = *(const f16x8*)&Bs[n * 16 + lrow][ks * 32 + lk];
#pragma unroll
        for (int m = 0; m < 2; ++m)
#pragma unroll
            for (int n = 0; n < 8; ++n)
                acc[m][n] = __builtin_amdgcn_mfma_f32_16x16x32_f16(af[m], bf[n], acc[m][n], 0, 0, 0);
    }
    int og = (l >> 4) * 4;
#pragma unroll
    for (int m = 0; m < 2; ++m) {
#pragma unroll
        for (int n = 0; n < 4; ++n) {
            int h = n * 16 + lrow;
            float bb1 = b1[h], bb2 = b2[h];
#pragma unroll
            for (int rr = 0; rr < 4; ++rr) {
                int R = row0 + m * 16 + og + rr;
                if (R < NR) {
                    float g1 = acc[m][n][rr] + bb1;
                    float g2 = acc[m][n + 4][rr] + bb2;
                    float e = __expf(2.f * g1);
                    float th = 1.f - 2.f / (e + 1.f);
                    float sg = 1.f / (1.f + __expf(-g2));
                    out[(size_t)R * 64 + h] = (f16)(th * sg);
                }
            }
        }
    }
}

// TCN2
__global__ __launch_bounds__(256) void k_tcn2g(const f16* __restrict__ A,
                                               const f16* __restrict__ Bw,
                                               const float* __restrict__ b1,
                                               const float* __restrict__ b2,
                                               float* __restrict__ out)
{
    __shared__ f16 Bs[128][200];
    int tid = threadIdx.x;
#pragma unroll
    for (int i = 0; i < 12; ++i) {
        int c = tid + i * 256;
        int row = c / 24, seg = (c % 24) * 8;
        *(f16x8*)&Bs[row][seg] = *(const f16x8*)&Bw[row * 192 + seg];
    }
    __syncthreads();

    int w = tid >> 6, l = tid & 63;
    int row0 = blockIdx.x * 128 + w * 32;
    int lrow = l & 15, lk = (l >> 4) * 8;

    size_t abase[2];
#pragma unroll
    for (int m = 0; m < 2; ++m) {
        int rr = row0 + m * 16 + lrow;
        int rc = (rr < NR2) ? rr : NR2 - 1;
        int n = rc >> 3, t = rc & 7;
        abase[m] = (size_t)n * FF + t * 64 + lk;
    }
    f32x4 acc[2][8];
#pragma unroll
    for (int m = 0; m < 2; ++m)
#pragma unroll
        for (int n = 0; n < 8; ++n)
            acc[m][n] = (f32x4){0.f, 0.f, 0.f, 0.f};

#pragma unroll
    for (int ks = 0; ks < 6; ++ks) {
        f16x8 af[2], bf[8];
#pragma unroll
        for (int m = 0; m < 2; ++m)
            af[m] = *(const f16x8*)&A[abase[m] + ks * 32];
#pragma unroll
        for (int n = 0; n < 8; ++n)
            bf[n] = *(const f16x8*)&Bs[n * 16 + lrow][ks * 32 + lk];
#pragma unroll
        for (int m = 0; m < 2; ++m)
#pragma unroll
            for (int n = 0; n < 8; ++n)
                acc[m][n] = __builtin_amdgcn_mfma_f32_16x16x32_f16(af[m], bf[n], acc[m][n], 0, 0, 0);
    }
    int og = (l >> 4) * 4;
#pragma unroll
    for (int m = 0; m < 2; ++m) {
#pragma unroll
        for (int n = 0; n < 4; ++n) {
            int c = n * 16 + lrow;
            float bb1 = b1[c], bb2 = b2[c];
#pragma unroll
            for (int rr = 0; rr < 4; ++rr) {
                int R = row0 + m * 16 + og + rr;
                if (R < NR2) {
                    float g1 = acc[m][n][rr] + bb1;
                    float g2 = acc[m][n + 4][rr] + bb2;
                    float e = __expf(2.f * g1);
                    float th = 1.f - 2.f / (e + 1.f);
                    float sg = 1.f / (1.f + __expf(-g2));
                    int n2 = R >> 3, t2 = R & 7;
                    out[(size_t)n2 * (CCH * TOUT) + c * TOUT + t2] = th * sg;
                }
            }
        }
    }
}

// ---------------- scan (thread-coarsened) + dis fold ------------------------
__global__ __launch_bounds__(1024) void k_scan(const int* __restrict__ cnt,
                      int* __restrict__ rowptr,
                      const float* __restrict__ degp, const float* __restrict__ degn,
                      float* __restrict__ disp, float* __restrict__ disn)
{
    int tid = threadIdx.x;
    for (int i = tid; i < NN; i += 1024) {
        disp[i] = 1.f / sqrtf(degp[i] + 1.f);
        disn[i] = 1.f / sqrtf(degn[i] + 1.f);
    }
    __shared__ int part[1024];
    int base = tid * 10;
    int loc[10];
    int sum = 0;
    if (tid < 1000) {
#pragma unroll
        for (int j = 0; j < 10; ++j) { loc[j] = sum; sum += cnt[base + j]; }
    }
    part[tid] = (tid < 1000) ? sum : 0;
    __syncthreads();
    for (int off = 1; off < 1024; off <<= 1) {
        int t = (tid >= off) ? part[tid - off] : 0;
        __syncthreads();
        part[tid] += t;
        __syncthreads();
    }
    int prefix = (tid > 0) ? part[tid - 1] : 0;
    if (tid < 1000) {
#pragma unroll
        for (int j = 0; j < 10; ++j) rowptr[base + j] = prefix + loc[j];
    }
    if (tid == 0) rowptr[NN] = part[1023];
}

// ---------------- CSR fill ---------------------------------------------------
__global__ void k_fill(const int* __restrict__ ei, const float* __restrict__ ea,
                       const int* __restrict__ rowptr, int* __restrict__ cursor,
                       const float* __restrict__ disp, const float* __restrict__ disn,
                       int* __restrict__ colsrc, float* __restrict__ normp, float* __restrict__ normn)
{
    int e = blockIdx.x * blockDim.x + threadIdx.x;
    if (e >= NE) return;
    int s = ei[e], d = ei[NE + e];
    int slot = atomicAdd(&cursor[d], 1);
    int idx = rowptr[d] + slot;
    colsrc[idx] = s;
    normp[idx] = disp[s] * (ea[e * 2 + 0] + 1.f) * disp[d];
    normn[idx] = disn[s] * (ea[e * 2 + 1] + 1.f) * disn[d];
}

// ---------------- permute rows+cols to f' order (batched via z) -------------
__global__ __launch_bounds__(640) void k_perm2(const f16* __restrict__ Wt0,
                                               f16* __restrict__ Wp, f16* __restrict__ Wn)
{
    __shared__ f16 row[FF];
    const f16* src = Wt0 + (size_t)blockIdx.z * FF * FF;
    f16* dst = blockIdx.z ? Wn : Wp;
    int np = blockIdx.x;
    int n = (np & 63) * 10 + (np >> 6);
    int tid = threadIdx.x;
    row[tid] = src[(size_t)n * FF + tid];
    __syncthreads();
    int k = (tid & 63) * 10 + (tid >> 6);
    dst[(size_t)np * FF + tid] = row[k];
}

// ---------------- f16 MFMA GEMM, double-buffered; optional 2-variant via z --
__global__ __launch_bounds__(256) void k_gemm16z(const f16* __restrict__ A,
                                                 const f16* __restrict__ Bt0,
                                                 const f16* __restrict__ Bt1,
                                                 f16* __restrict__ C0,
                                                 f16* __restrict__ C1, int M)
{
    const f16* Bt = blockIdx.z ? Bt1 : Bt0;
    f16* C = blockIdx.z ? C1 : C0;
    __shared__ f16 As[2][128 * 32];
    __shared__ f16 Bs[2][64 * 32];
    int tid = threadIdx.x;
    int row0 = blockIdx.y * 128;
    int col0 = blockIdx.x * 64;
    int w = tid >> 6, l = tid & 63;
    int wr = (w >> 1) * 64;
    int wc = (w & 1) * 32;
    int lrow = l & 15;
    int lk = (l >> 4) * 8;

    int arow = w * 32 + (l >> 2);
    int brow = w * 16 + (l >> 2);
    int seg  = (l & 3) * 8;

    f32x4 acc[4][2];
#pragma unroll
    for (int m = 0; m < 4; ++m)
#pragma unroll
        for (int n = 0; n < 2; ++n)
            acc[m][n] = (f32x4){0.f, 0.f, 0.f, 0.f};

    GLD_LDS(&A[(size_t)(row0 + arow) * FF + seg],       &As[0][w * 1024]);
    GLD_LDS(&A[(size_t)(row0 + arow + 16) * FF + seg],  &As[0][w * 1024 + 512]);
    GLD_LDS(&Bt[(size_t)(col0 + brow) * FF + seg],      &Bs[0][w * 512]);
    __syncthreads();

    int cur = 0;
    for (int step = 0; step < 20; ++step) {
        if (step < 19) {
            int k1 = (step + 1) * 32;
            GLD_LDS(&A[(size_t)(row0 + arow) * FF + k1 + seg],       &As[cur ^ 1][w * 1024]);
            GLD_LDS(&A[(size_t)(row0 + arow + 16) * FF + k1 + seg],  &As[cur ^ 1][w * 1024 + 512]);
            GLD_LDS(&Bt[(size_t)(col0 + brow) * FF + k1 + seg],      &Bs[cur ^ 1][w * 512]);
        }
        f16x8 af[4], bf[2];
#pragma unroll
        for (int m = 0; m < 4; ++m)
            af[m] = *(const f16x8*)&As[cur][(wr + m * 16 + lrow) * 32 + lk];
#pragma unroll
        for (int n = 0; n < 2; ++n)
            bf[n] = *(const f16x8*)&Bs[cur][(wc + n * 16 + lrow) * 32 + lk];
#pragma unroll
        for (int m = 0; m < 4; ++m)
#pragma unroll
            for (int n = 0; n < 2; ++n)
                acc[m][n] = __builtin_amdgcn_mfma_f32_16x16x32_f16(af[m], bf[n], acc[m][n], 0, 0, 0);
        __syncthreads();
        cur ^= 1;
    }
    int orow = (l >> 4) * 4;
#pragma unroll
    for (int m = 0; m < 4; ++m) {
#pragma unroll
        for (int r = 0; r < 4; ++r) {
            int rr = row0 + wr + m * 16 + orow + r;
            if (rr < M) {
#pragma unroll
                for (int n = 0; n < 2; ++n)
                    C[(size_t)rr * FF + col0 + wc + n * 16 + lrow] = (f16)acc[m][n][r];
            }
        }
    }
}

// ---------------- GCN aggregate; optional 2-variant via blockIdx.y ----------
__global__ __launch_bounds__(128) void k_agg2(const f16* __restrict__ src0,
                      const f16* __restrict__ src1,
                      const int* __restrict__ rowptr, const int* __restrict__ colsrc,
                      const float* __restrict__ normp, const float* __restrict__ normn,
                      const float* __restrict__ disp, const float* __restrict__ disn,
                      const float* __restrict__ bp, const float* __restrict__ bn,
                      f16* __restrict__ out0, f16* __restrict__ out1)
{
    __shared__ int   s_idx[128];
    __shared__ float s_w[128];
    int vy = blockIdx.y;
    const f16* hsrc = vy ? src1 : src0;
    const float* enorm = vy ? normn : normp;
    const float* dis = vy ? disn : disp;
    const float* bias = vy ? bn : bp;
    f16* hout = vy ? out1 : out0;
    int d = blockIdx.x;
    int lane = threadIdx.x;
    int c0 = lane * 8;
    bool act = lane < 80;
    float v[8] = {0.f, 0.f, 0.f, 0.f, 0.f, 0.f, 0.f, 0.f};
    if (act) {
        float selfw = dis[d] * dis[d];
        f16x8 self = *(const f16x8*)&hsrc[(size_t)d * FF + c0];
#pragma unroll
        for (int j = 0; j < 8; ++j) v[j] = selfw * (float)self[j];
    }
    int beg = rowptr[d], end = rowptr[d + 1];
    for (int base = beg; base < end; base += 128) {
        int cnt = (end - base < 128) ? (end - base) : 128;
        __syncthreads();
        if (lane < cnt) {
            s_idx[lane] = colsrc[base + lane];
            s_w[lane]   = enorm[base + lane];
        }
        __syncthreads();
        if (act) {
            for (int i = 0; i < cnt; ++i) {
                f16x8 p = *(const f16x8*)&hsrc[(size_t)s_idx[i] * FF + c0];
                float w = s_w[i];
#pragma unroll
                for (int j = 0; j < 8; ++j) v[j] += w * (float)p[j];
            }
        }
    }
    if (act) {
        f16x8 o;
#pragma unroll
        for (int j = 0; j < 8; ++j) {
            int c = c0 + j;
            o[j] = (f16)fmaxf(v[j] + bias[(c & 63) * 10 + (c >> 6)], 0.f);
        }
        *(f16x8*)&hout[(size_t)d * FF + c0] = o;
    }
}

// ---------------- GReTo mix as MFMA GEMM (f16 out) --------------------------
__global__ __launch_bounds__(256) void k_greto2(const f16* __restrict__ h1,
                        const f16* __restrict__ h2, const f16* __restrict__ h3,
                        const f16* __restrict__ hneg, const float* __restrict__ psi,
                        const f16* __restrict__ gWt, const float* __restrict__ gb,
                        f16* __restrict__ out)
{
    __shared__ f16 As[128][132];
    __shared__ f16 Bs[64][132];
    int tid = threadIdx.x;
    int row0 = blockIdx.x * 128;

    for (int cb = tid; cb < 1024; cb += 256) {
        int d = cb >> 4, seg = (cb & 15) * 8;
        *(f16x8*)&Bs[d][seg] = *(const f16x8*)&gWt[d * 128 + seg];
    }
    int lr = tid >> 1, side = tid & 1;
    int r = row0 + lr;
    if (r < NR) {
        int n = r / 10, t = r - (r / 10) * 10;
        size_t base = (size_t)n * FF + t * 64;
        if (side == 0) {
            float p0 = psi[n * 3], p1 = psi[n * 3 + 1], p2 = psi[n * 3 + 2];
#pragma unroll
            for (int i = 0; i < 8; ++i) {
                f16x8 a = *(const f16x8*)&h1[base + i * 8];
                f16x8 b = *(const f16x8*)&h2[base + i * 8];
                f16x8 c = *(const f16x8*)&h3[base + i * 8];
                f16x8 o;
#pragma unroll
                for (int j = 0; j < 8; ++j)
                    o[j] = (f16)(p0 * (float)a[j] + p1 * (float)b[j] + p2 * (float)c[j]);
                *(f16x8*)&As[lr][i * 8] = o;
            }
        } else {
#pragma unroll
            for (int i = 0; i < 8; ++i)
                *(f16x8*)&As[lr][64 + i * 8] = *(const f16x8*)&hneg[base + i * 8];
        }
    } else {
        f16x8 z = {};
#pragma unroll
        for (int i = 0; i < 8; ++i)
            *(f16x8*)&As[lr][side * 64 + i * 8] = z;
    }
    __syncthreads();

    int w = tid >> 6, l = tid & 63;
    int wr = w * 32;
    int lrow = l & 15;
    int lk = (l >> 4) * 8;
    f32x4 acc[2][4];
#pragma unroll
    for (int m = 0; m < 2; ++m)
#pragma unroll
        for (int n = 0; n < 4; ++n)
            acc[m][n] = (f32x4){0.f, 0.f, 0.f, 0.f};
#pragma unroll
    for (int ks = 0; ks < 4; ++ks) {
        f16x8 af[2], bf[4];
#pragma unroll
        for (int m = 0; m < 2; ++m)
            af[m] = *(const f16x8*)&As[wr + m * 16 + lrow][ks * 32 + lk];
#pragma unroll
        for (int n = 0; n < 4; ++n)
            bf[n] = *(const f16x8*)&Bs[n * 16 + lrow][ks * 32 + lk];
#pragma unroll
        for (int m = 0; m < 2; ++m)
#pragma unroll
            for (int n = 0; n < 4; ++n)
                acc[m][n] = __builtin_amdgcn_mfma_f32_16x16x32_f16(af[m], bf[n], acc[m][n], 0, 0, 0);
    }
    int orow = (l >> 4) * 4;
#pragma unroll
    for (int m = 0; m < 2; ++m) {
#pragma unroll
        for (int rr = 0; rr < 4; ++rr) {
            int ro = row0 + wr + m * 16 + orow + rr;
            if (ro < NR) {
#pragma unroll
                for (int n = 0; n < 4; ++n) {
                    int col = n * 16 + lrow;
                    out[(size_t)ro * 64 + col] = (f16)fmaxf(acc[m][n][rr] + gb[col], 0.f);
                }
            }
        }
    }
}

extern "C" void kernel_launch(void* const* d_in, const int* in_sizes, int n_in,
                              void* d_out, int out_size, void* d_ws, size_t ws_size,
                              hipStream_t stream)
{
    const float* x     = (const float*)d_in[0];
    const int*   ei    = (const int*)  d_in[1];
    const float* ea    = (const float*)d_in[2];
    const float* ndt   = (const float*)d_in[3];
    const float* tc1w1 = (const float*)d_in[4];
    const float* tc1b1 = (const float*)d_in[5];
    const float* tc1w2 = (const float*)d_in[6];
    const float* tc1b2 = (const float*)d_in[7];
    const float* Wpos  = (const float*)d_in[8];
    const float* bpos  = (const float*)d_in[9];
    const float* Wneg  = (const float*)d_in[10];
    const float* bneg  = (const float*)d_in[11];
    const float* greW  = (const float*)d_in[12];
    const float* greb  = (const float*)d_in[13];
    const float* psiW1 = (const float*)d_in[14];
    const float* psib1 = (const float*)d_in[15];
    const float* psiW2 = (const float*)d_in[16];
    const float* psib2 = (const float*)d_in[17];
    const float* tc2w1 = (const float*)d_in[18];
    const float* tc2b1 = (const float*)d_in[19];
    const float* tc2w2 = (const float*)d_in[20];
    const float* tc2b2 = (const float*)d_in[21];
    float* out = (float*)d_out;

    char* p = (char*)d_ws;
    int*   cnt   = (int*)p;   p += (size_t)NN * 4;
    int*   cursor= (int*)p;   p += (size_t)NN * 4;
    float* degp  = (float*)p; p += (size_t)NN * 4;
    float* degn  = (float*)p; p += (size_t)NN * 4;
    f16*   xT    = (f16*)p;   p += (size_t)NN * CCH * TIN * 2;
    f16*   out0h = (f16*)p;   p += (size_t)NN * FF * 2;
    f16*   h1    = (f16*)p;   p += (size_t)NN * FF * 2;
    f16*   h2    = (f16*)p;   p += (size_t)NN * FF * 2;
    f16*   h3    = (f16*)p;   p += (size_t)NN * FF * 2;
    f16*   hneg  = (f16*)p;   p += (size_t)NN * FF * 2;
    f16*   Cb16  = (f16*)p;   p += (size_t)NN * FF * 2;
    f16*   Cn16  = (f16*)p;   p += (size_t)NN * FF * 2;
    f16*   Gbuf  = (f16*)p;   p += (size_t)NN * FF * 2;
    f16*   Wtp   = (f16*)p;   p += (size_t)FF * FF * 2;
    f16*   Wtn   = (f16*)p;   p += (size_t)FF * FF * 2;
    f16*   Wtmp  = (f16*)p;   p += (size_t)2 * FF * FF * 2;
    f16*   gWt   = (f16*)p;   p += (size_t)128 * 64 * 2;
    f16*   Bw1   = (f16*)p;   p += (size_t)128 * 192 * 2;
    f16*   Bw2   = (f16*)p;   p += (size_t)128 * 192 * 2;
    float* psib  = (float*)p; p += (size_t)NN * 3 * 4;
    float* disp  = (float*)p; p += (size_t)NN * 4;
    float* disn  = (float*)p; p += (size_t)NN * 4;
    float* normp = (float*)p; p += (size_t)NE * 4;
    float* normn = (float*)p; p += (size_t)NE * 4;
    int* rowptr  = (int*)p;   p += (size_t)(NN + 1) * 4;
    int* colsrc  = (int*)p;   p += (size_t)NE * 4;

    (void)hipMemsetAsync(cnt, 0, (size_t)4 * NN * 4, stream);

    k_prep<<<PB_WS, 256, 0, stream>>>(x, xT, tc1w1, tc1w2, tc2w1, tc2w2, Bw1, Bw2,
                                      ndt, psiW1, psib1, psiW2, psib2, psib,
                                      greW, gWt, ei, ea, cnt, degp, degn,
                                      Wpos, Wneg, Wtmp);
    k_scan<<<1, 1024, 0, stream>>>(cnt, rowptr, degp, degn, disp, disn);
    k_fill<<<(NE + 255) / 256, 256, 0, stream>>>(ei, ea, rowptr, cursor, disp, disn,
                                                 colsrc, normp, normn);
    dim3 pgrid(FF, 1, 2);
    k_perm2<<<pgrid, 640, 0, stream>>>(Wtmp, Wtp, Wtn);
    k_tcn1g<<<(NR + 127) / 128, 256, 0, stream>>>(xT, Bw1, tc1b1, tc1b2, out0h);

    dim3 ggrid2(FF / 64, (NN + 127) / 128, 2);   // fused pos+neg first gemm
    dim3 ggrid1(FF / 64, (NN + 127) / 128, 1);
    dim3 agrid2(NN, 2);
    dim3 agrid1(NN, 1);
    // hop 1 (pos) + negative branch, fused
    k_gemm16z<<<ggrid2, 256, 0, stream>>>(out0h, Wtp, Wtn, Cb16, Cn16, NN);
    k_agg2<<<agrid2, 128, 0, stream>>>(Cb16, Cn16, rowptr, colsrc, normp, normn,
                                       disp, disn, bpos, bneg, h1, hneg);
    // hop 2
    k_gemm16z<<<ggrid1, 256, 0, stream>>>(h1, Wtp, Wtp, Cb16, Cb16, NN);
    k_agg2<<<agrid1, 128, 0, stream>>>(Cb16, Cb16, rowptr, colsrc, normp, normp,
                                       disp, disp, bpos, bpos, h2, h2);
    // hop 3
    k_gemm16z<<<ggrid1, 256, 0, stream>>>(h2, Wtp, Wtp, Cb16, Cb16, NN);
    k_agg2<<<agrid1, 128, 0, stream>>>(Cb16, Cb16, rowptr, colsrc, normp, normp,
                                       disp, disp, bpos, bpos, h3, h3);
    // GReTo channel mix (MFMA) + psi accumulation + relu -> f16
    k_greto2<<<(NR + 127) / 128, 256, 0, stream>>>(h1, h2, h3, hneg, psib, gWt, greb, Gbuf);
    // final gated TCN as direct GEMM
    k_tcn2g<<<(NR2 + 127) / 128, 256, 0, stream>>>(Gbuf, Bw2, tc2b1, tc2b2, out);
}